// Round 3
// baseline (1987.242 us; speedup 1.0000x reference)
//
#include <hip/hip_runtime.h>
#include <hip/hip_bf16.h>
#include <cstdint>

typedef unsigned short u16;

#define C_DIM 384
#define NHEAD 12
#define HD    32
#define NTOK  343     // tokens per window (7^3)
#define NWIN  64
#define LTOT  21952   // 28^3
#define SIDE  28

__device__ __forceinline__ float u2f(u16 u) {
    return __uint_as_float(((unsigned int)u) << 16);
}
__device__ __forceinline__ float lof(unsigned int u) { return __uint_as_float(u << 16); }
__device__ __forceinline__ float hif(unsigned int u) { return __uint_as_float(u & 0xffff0000u); }
__device__ __forceinline__ u16 f2b(float f) {
    unsigned int u = __float_as_uint(f);
    return (u16)((u + 0x7fffu + ((u >> 16) & 1u)) >> 16);   // RNE
}
__device__ __forceinline__ float gelu_tanh(float x) {
    float x3 = x * x * x;
    return 0.5f * x * (1.f + tanhf(0.7978845608028654f * (x + 0.044715f * x3)));
}

// ---------------------------------------------------------------------------
// Kernel 1: dual LayerNorm (skip f32, x_up f32) + window partition -> bf16.
// One wave per token, lane handles channels lane+64j (j=0..5).
// ---------------------------------------------------------------------------
__global__ __launch_bounds__(256) void k_lnprep(
    const float* __restrict__ skip, const float* __restrict__ xup,
    const float* __restrict__ g, const float* __restrict__ bta,
    u16* __restrict__ skW, u16* __restrict__ qW)
{
    int t = blockIdx.x * 4 + (threadIdx.x >> 6);
    int lane = threadIdx.x & 63;
    const float* ps = skip + (size_t)t * C_DIM;
    const float* px = xup + (size_t)t * C_DIM;
    float vs[6], vx[6];
    float s1 = 0.f, s2 = 0.f, x1 = 0.f, x2 = 0.f;
#pragma unroll
    for (int j = 0; j < 6; j++) {
        float a = ps[lane + j * 64];
        float b = px[lane + j * 64];
        vs[j] = a; vx[j] = b;
        s1 += a; s2 += a * a; x1 += b; x2 += b * b;
    }
#pragma unroll
    for (int off = 32; off; off >>= 1) {
        s1 += __shfl_xor(s1, off);
        s2 += __shfl_xor(s2, off);
        x1 += __shfl_xor(x1, off);
        x2 += __shfl_xor(x2, off);
    }
    float ms = s1 * (1.f / 384.f), mx = x1 * (1.f / 384.f);
    float rs = rsqrtf(fmaxf(s2 * (1.f / 384.f) - ms * ms, 0.f) + 1e-5f);
    float rx = rsqrtf(fmaxf(x2 * (1.f / 384.f) - mx * mx, 0.f) + 1e-5f);
    // window mapping
    int d = t / 784, rem = t % 784, hh = rem / 28, ww = rem % 28;
    int win = (d / 7) * 16 + (hh / 7) * 4 + (ww / 7);
    int n = (d % 7) * 49 + (hh % 7) * 7 + (ww % 7);
    size_t dst = ((size_t)(win * NTOK + n)) * C_DIM + lane;
#pragma unroll
    for (int j = 0; j < 6; j++) {
        int c = lane + j * 64;
        float gg = g[c], bb = bta[c];
        skW[dst + j * 64] = f2b((vs[j] - ms) * rs * gg + bb);
        qW[dst + j * 64]  = f2b((vx[j] - mx) * rx * gg + bb);
    }
}

// ---------------------------------------------------------------------------
// Kernel 5: LayerNorm of x2 (bf16) -> lnx (bf16), token layout.
// ---------------------------------------------------------------------------
__global__ __launch_bounds__(256) void k_ln2(
    const u16* __restrict__ x2, const float* __restrict__ g,
    const float* __restrict__ bta, u16* __restrict__ lnx)
{
    int t = blockIdx.x * 4 + (threadIdx.x >> 6);
    int lane = threadIdx.x & 63;
    const u16* p = x2 + (size_t)t * C_DIM;
    float v[6];
    float s1 = 0.f, s2 = 0.f;
#pragma unroll
    for (int j = 0; j < 6; j++) {
        float a = u2f(p[lane + j * 64]);
        v[j] = a; s1 += a; s2 += a * a;
    }
#pragma unroll
    for (int off = 32; off; off >>= 1) {
        s1 += __shfl_xor(s1, off);
        s2 += __shfl_xor(s2, off);
    }
    float m = s1 * (1.f / 384.f);
    float r = rsqrtf(fmaxf(s2 * (1.f / 384.f) - m * m, 0.f) + 1e-5f);
    size_t dst = (size_t)t * C_DIM + lane;
#pragma unroll
    for (int j = 0; j < 6; j++) {
        int c = lane + j * 64;
        lnx[dst + j * 64] = f2b((v[j] - m) * r * g[c] + bta[c]);
    }
}

// ---------------------------------------------------------------------------
// Shared fp32-accumulate GEMM core: 64x64 tile, BK=16, 256 threads, 4x4/thread.
// A: MxK row-major bf16 (internal), B: KxN row-major f32 (weights).
// M,N multiples of 64, K multiple of 16.
// ---------------------------------------------------------------------------
__device__ __forceinline__ void gemm_core(
    const u16* __restrict__ A, const float* __restrict__ B,
    int Ka, int Nb, int rowBase, int colBase, int tid,
    float (*As)[68], float (*Bs)[68], float acc[4][4])
{
    const int ar = tid >> 2;          // 0..63
    const int ak = (tid & 3) << 2;    // 0,4,8,12
    const int br = tid >> 4;          // 0..15
    const int bc = (tid & 15) << 2;   // 0..60
    const int ty = tid >> 4, tx = tid & 15;

    ushort4 ua = *(const ushort4*)(A + (size_t)(rowBase + ar) * Ka + ak);
    float4  ub = *(const float4*)(B + (size_t)br * Nb + colBase + bc);

    for (int kk = 0; kk < Ka; kk += 16) {
        As[ak + 0][ar] = u2f(ua.x); As[ak + 1][ar] = u2f(ua.y);
        As[ak + 2][ar] = u2f(ua.z); As[ak + 3][ar] = u2f(ua.w);
        Bs[br][bc + 0] = ub.x; Bs[br][bc + 1] = ub.y;
        Bs[br][bc + 2] = ub.z; Bs[br][bc + 3] = ub.w;
        __syncthreads();
        if (kk + 16 < Ka) {   // prefetch next chunk while computing
            ua = *(const ushort4*)(A + (size_t)(rowBase + ar) * Ka + kk + 16 + ak);
            ub = *(const float4*)(B + (size_t)(kk + 16 + br) * Nb + colBase + bc);
        }
#pragma unroll
        for (int kc = 0; kc < 16; kc++) {
            float4 av = *(const float4*)&As[kc][ty << 2];
            float4 bv = *(const float4*)&Bs[kc][tx << 2];
            float aa[4] = { av.x, av.y, av.z, av.w };
            float bb[4] = { bv.x, bv.y, bv.z, bv.w };
#pragma unroll
            for (int i = 0; i < 4; i++)
#pragma unroll
                for (int j = 0; j < 4; j++)
                    acc[i][j] = fmaf(aa[i], bb[j], acc[i][j]);
        }
        __syncthreads();
    }
}

// GEMM variant: KV projection.  A=skW (windowed rows, bf16), B=kv_w (384x768 f32).
// Output split into K/V (bf16) with layout (w, head, n, d).
__global__ __launch_bounds__(256) void k_gemm_kv(
    const u16* __restrict__ A, const float* __restrict__ W, const float* __restrict__ bias,
    u16* __restrict__ Kb, u16* __restrict__ Vb)
{
    __shared__ __align__(16) float As[16][68];
    __shared__ __align__(16) float Bs[16][68];
    float acc[4][4] = {};
    int tid = threadIdx.x;
    int rowBase = blockIdx.x * 64, colBase = blockIdx.y * 64;
    gemm_core(A, W, 384, 768, rowBase, colBase, tid, As, Bs, acc);
    int ty = tid >> 4, tx = tid & 15;
#pragma unroll
    for (int i = 0; i < 4; i++) {
        int r = rowBase + (ty << 2) + i;
        int w = r / NTOK, nn = r % NTOK;
#pragma unroll
        for (int j = 0; j < 4; j++) {
            int col = colBase + (tx << 2) + j;
            float val = acc[i][j] + bias[col];
            int isv = col >= 384;
            int remc = col - (isv ? 384 : 0);
            int hh = remc >> 5, dd = remc & 31;
            size_t dst = ((size_t)((w * NHEAD + hh) * NTOK + nn)) * HD + dd;
            (isv ? Vb : Kb)[dst] = f2b(val);
        }
    }
}

// GEMM variant: output projection + bias + residual (skip + x_up, f32). Out bf16.
__global__ __launch_bounds__(256) void k_gemm_proj(
    const u16* __restrict__ A, const float* __restrict__ W, const float* __restrict__ bias,
    const float* __restrict__ skip, const float* __restrict__ xup, u16* __restrict__ x2)
{
    __shared__ __align__(16) float As[16][68];
    __shared__ __align__(16) float Bs[16][68];
    float acc[4][4] = {};
    int tid = threadIdx.x;
    int rowBase = blockIdx.x * 64, colBase = blockIdx.y * 64;
    gemm_core(A, W, 384, 384, rowBase, colBase, tid, As, Bs, acc);
    int ty = tid >> 4, tx = tid & 15;
#pragma unroll
    for (int i = 0; i < 4; i++) {
        size_t r = rowBase + (ty << 2) + i;
#pragma unroll
        for (int j = 0; j < 4; j++) {
            int col = colBase + (tx << 2) + j;
            size_t idx = r * C_DIM + col;
            x2[idx] = f2b(acc[i][j] + bias[col] + skip[idx] + xup[idx]);
        }
    }
}

// GEMM variant: MLP layer 1 + bias + gelu.  Out bf16 into a CHUNK buffer.
__global__ __launch_bounds__(256) void k_gemm_mlp1(
    const u16* __restrict__ A, const float* __restrict__ W, const float* __restrict__ bias,
    u16* __restrict__ h1c, int rowOfs)
{
    __shared__ __align__(16) float As[16][68];
    __shared__ __align__(16) float Bs[16][68];
    float acc[4][4] = {};
    int tid = threadIdx.x;
    int rowBase = rowOfs + blockIdx.x * 64, colBase = blockIdx.y * 64;
    gemm_core(A, W, 384, 1536, rowBase, colBase, tid, As, Bs, acc);
    int ty = tid >> 4, tx = tid & 15;
#pragma unroll
    for (int i = 0; i < 4; i++) {
        size_t r = (size_t)(rowBase - rowOfs) + (ty << 2) + i;   // local row
#pragma unroll
        for (int j = 0; j < 4; j++) {
            int col = colBase + (tx << 2) + j;
            h1c[r * 1536 + col] = f2b(gelu_tanh(acc[i][j] + bias[col]));
        }
    }
}

// GEMM variant: MLP layer 2 + bias + residual x2 (bf16).  Out f32 (final).
__global__ __launch_bounds__(256) void k_gemm_mlp2(
    const u16* __restrict__ A, const float* __restrict__ W, const float* __restrict__ bias,
    const u16* __restrict__ x2, float* __restrict__ out, int rowOfs)
{
    __shared__ __align__(16) float As[16][68];
    __shared__ __align__(16) float Bs[16][68];
    float acc[4][4] = {};
    int tid = threadIdx.x;
    int rowBase = blockIdx.x * 64, colBase = blockIdx.y * 64;     // local rows
    gemm_core(A, W, 1536, 384, rowBase, colBase, tid, As, Bs, acc);
    int ty = tid >> 4, tx = tid & 15;
#pragma unroll
    for (int i = 0; i < 4; i++) {
        size_t rg = (size_t)rowOfs + rowBase + (ty << 2) + i;     // global row
        size_t rl = (size_t)rowBase + (ty << 2) + i;              // local row
#pragma unroll
        for (int j = 0; j < 4; j++) {
            int col = colBase + (tx << 2) + j;
            out[rg * C_DIM + col] = acc[i][j] + bias[col] + u2f(x2[rg * C_DIM + col]);
            (void)rl;
        }
    }
}

// ---------------------------------------------------------------------------
// Kernel 3: window attention. One block per (window, head); thread = query row.
// K/V (bf16) + rpb slice (f32) staged in LDS (52.7 KB). Online softmax.
// ---------------------------------------------------------------------------
__global__ __launch_bounds__(384) void k_attn(
    const u16* __restrict__ qW, const u16* __restrict__ Kb, const u16* __restrict__ Vb,
    const float* __restrict__ rpb, u16* __restrict__ oT)
{
    __shared__ __align__(16) u16 Ks[NTOK * HD];
    __shared__ __align__(16) u16 Vs[NTOK * HD];
    __shared__ float rp[2197];
    int w = blockIdx.x / NHEAD, h = blockIdx.x % NHEAD;
    int tid = threadIdx.x;
    size_t base = ((size_t)(w * NHEAD + h)) * NTOK * HD;
    for (int i = tid; i < NTOK * HD; i += 384) {
        Ks[i] = Kb[base + i];
        Vs[i] = Vb[base + i];
    }
    for (int i = tid; i < 2197; i += 384) rp[i] = rpb[i * NHEAD + h];
    __syncthreads();

    if (tid < NTOK) {
        int q = tid;
        int qz = q / 49, qy = (q / 7) % 7, qx = q % 7;
        float qr[32];
        const u16* qp = qW + ((size_t)(w * NTOK + q)) * C_DIM + h * HD;
#pragma unroll
        for (int d = 0; d < 32; d++) qr[d] = u2f(qp[d]) * 0.17677669529663687f; // hd^-0.5
        float m = -1e30f, l = 0.f, o[32];
#pragma unroll
        for (int d = 0; d < 32; d++) o[d] = 0.f;

        for (int k = 0; k < NTOK; k++) {
            int kz = k / 49, ky = (k / 7) % 7, kx = k % 7;
            float s = rp[(qz - kz + 6) * 169 + (qy - ky + 6) * 13 + (qx - kx + 6)];
            const uint4* kp = (const uint4*)(Ks + k * HD);
#pragma unroll
            for (int t4 = 0; t4 < 4; t4++) {
                uint4 u = kp[t4];
                int db = t4 * 8;
                s = fmaf(qr[db + 0], lof(u.x), s);
                s = fmaf(qr[db + 1], hif(u.x), s);
                s = fmaf(qr[db + 2], lof(u.y), s);
                s = fmaf(qr[db + 3], hif(u.y), s);
                s = fmaf(qr[db + 4], lof(u.z), s);
                s = fmaf(qr[db + 5], hif(u.z), s);
                s = fmaf(qr[db + 6], lof(u.w), s);
                s = fmaf(qr[db + 7], hif(u.w), s);
            }
            const uint4* vp = (const uint4*)(Vs + k * HD);
            if (s <= m) {
                float p = __expf(s - m);
                l += p;
#pragma unroll
                for (int t4 = 0; t4 < 4; t4++) {
                    uint4 u = vp[t4];
                    int db = t4 * 8;
                    o[db + 0] = fmaf(p, lof(u.x), o[db + 0]);
                    o[db + 1] = fmaf(p, hif(u.x), o[db + 1]);
                    o[db + 2] = fmaf(p, lof(u.y), o[db + 2]);
                    o[db + 3] = fmaf(p, hif(u.y), o[db + 3]);
                    o[db + 4] = fmaf(p, lof(u.z), o[db + 4]);
                    o[db + 5] = fmaf(p, hif(u.z), o[db + 5]);
                    o[db + 6] = fmaf(p, lof(u.w), o[db + 6]);
                    o[db + 7] = fmaf(p, hif(u.w), o[db + 7]);
                }
            } else {
                float rsc = __expf(m - s);
                m = s;
                l = fmaf(l, rsc, 1.f);
#pragma unroll
                for (int t4 = 0; t4 < 4; t4++) {
                    uint4 u = vp[t4];
                    int db = t4 * 8;
                    o[db + 0] = fmaf(o[db + 0], rsc, lof(u.x));
                    o[db + 1] = fmaf(o[db + 1], rsc, hif(u.x));
                    o[db + 2] = fmaf(o[db + 2], rsc, lof(u.y));
                    o[db + 3] = fmaf(o[db + 3], rsc, hif(u.y));
                    o[db + 4] = fmaf(o[db + 4], rsc, lof(u.z));
                    o[db + 5] = fmaf(o[db + 5], rsc, hif(u.z));
                    o[db + 6] = fmaf(o[db + 6], rsc, lof(u.w));
                    o[db + 7] = fmaf(o[db + 7], rsc, hif(u.w));
                }
            }
        }
        float rl = 1.f / l;
        // window-reverse: token index
        int wd = w >> 4, wh = (w >> 2) & 3, wwi = w & 3;
        int gd = wd * 7 + qz, gh = wh * 7 + qy, gw = wwi * 7 + qx;
        size_t tok = ((size_t)gd * SIDE + gh) * SIDE + gw;
        u16* op = oT + tok * C_DIM + h * HD;
#pragma unroll
        for (int d = 0; d < 32; d++) op[d] = f2b(o[d] * rl);
    }
}

// ---------------------------------------------------------------------------
// Workspace plan (4 x BUF = 67,436,544 bytes total), BUF = L*C*2 = 16,859,136:
//   s0: skW  -> (dead after kv)   oT
//   s1: qW   -> (dead after attn) x2 (bf16)
//   s2: Kb   -> (dead after attn) lnx
//   s3: Vb   -> (dead after attn) h1 chunk (9.6 MB <= BUF)
// MLP runs in 7 chunks of 3136 rows.
// ---------------------------------------------------------------------------
extern "C" void kernel_launch(void* const* d_in, const int* in_sizes, int n_in,
                              void* d_out, int out_size, void* d_ws, size_t ws_size,
                              hipStream_t stream)
{
    const float* skip = (const float*)d_in[0];
    const float* xup  = (const float*)d_in[1];
    // d_in[2..4] = D,H,W scalars (28) — hard-coded
    const float* ln1g = (const float*)d_in[5];
    const float* ln1b = (const float*)d_in[6];
    const float* kvw  = (const float*)d_in[7];
    const float* kvb  = (const float*)d_in[8];
    const float* rpb  = (const float*)d_in[9];
    const float* pw   = (const float*)d_in[10];
    const float* pb   = (const float*)d_in[11];
    const float* ln2g = (const float*)d_in[12];
    const float* ln2b = (const float*)d_in[13];
    const float* w1   = (const float*)d_in[14];
    const float* b1   = (const float*)d_in[15];
    const float* w2   = (const float*)d_in[16];
    const float* b2   = (const float*)d_in[17];
    float* out = (float*)d_out;

    char* ws = (char*)d_ws;
    const size_t BUFB = (size_t)LTOT * C_DIM * 2;   // 16,859,136 B
    u16* skW = (u16*)(ws);
    u16* qW  = (u16*)(ws + BUFB);
    u16* Kb  = (u16*)(ws + 2 * BUFB);
    u16* Vb  = (u16*)(ws + 3 * BUFB);
    u16* oT  = (u16*)(ws);                  // overlays skW (dead)
    u16* x2  = (u16*)(ws + BUFB);           // overlays qW (dead)
    u16* lnx = (u16*)(ws + 2 * BUFB);       // overlays Kb (dead)
    u16* h1c = (u16*)(ws + 3 * BUFB);       // overlays Vb (dead)

    k_lnprep<<<LTOT / 4, 256, 0, stream>>>(skip, xup, ln1g, ln1b, skW, qW);
    k_gemm_kv<<<dim3(343, 12), 256, 0, stream>>>(skW, kvw, kvb, Kb, Vb);
    k_attn<<<NWIN * NHEAD, 384, 0, stream>>>(qW, Kb, Vb, rpb, oT);
    k_gemm_proj<<<dim3(343, 6), 256, 0, stream>>>(oT, pw, pb, skip, xup, x2);
    k_ln2<<<LTOT / 4, 256, 0, stream>>>(x2, ln2g, ln2b, lnx);
    for (int c = 0; c < 7; c++) {
        int rowOfs = c * 3136;   // 49 blocks of 64 rows per chunk
        k_gemm_mlp1<<<dim3(49, 24), 256, 0, stream>>>(lnx, w1, b1, h1c, rowOfs);
        k_gemm_mlp2<<<dim3(49, 6), 256, 0, stream>>>(h1c, w2, b2, x2, out, rowOfs);
    }
}

// Round 4
// 961.382 us; speedup vs baseline: 2.0671x; 2.0671x over previous
//
#include <hip/hip_runtime.h>
#include <hip/hip_bf16.h>
#include <cstdint>

typedef unsigned short u16;
typedef short s16x8 __attribute__((ext_vector_type(8)));
typedef float f32x4 __attribute__((ext_vector_type(4)));

#define C_DIM 384
#define NHEAD 12
#define HD    32
#define NTOK  343     // tokens per window (7^3)
#define NWIN  64
#define LTOT  21952   // 28^3
#define SIDE  28

__device__ __forceinline__ float u2f(u16 u) {
    return __uint_as_float(((unsigned int)u) << 16);
}
__device__ __forceinline__ float lof(unsigned int u) { return __uint_as_float(u << 16); }
__device__ __forceinline__ float hif(unsigned int u) { return __uint_as_float(u & 0xffff0000u); }
__device__ __forceinline__ u16 f2b(float f) {
    unsigned int u = __float_as_uint(f);
    return (u16)((u + 0x7fffu + ((u >> 16) & 1u)) >> 16);   // RNE
}
__device__ __forceinline__ float gelu_tanh(float x) {
    float x3 = x * x * x;
    return 0.5f * x * (1.f + tanhf(0.7978845608028654f * (x + 0.044715f * x3)));
}

// ---------------------------------------------------------------------------
// Weight transpose + f32->bf16: Wt[n][k] = bf16(W[k][n]).  W is KxN row-major.
// 64x64 tiles via LDS; coalesced global reads and writes.
// ---------------------------------------------------------------------------
__global__ __launch_bounds__(256) void k_wt(
    const float* __restrict__ W, u16* __restrict__ Wt, int K, int N)
{
    __shared__ float T[64][65];
    int k0 = blockIdx.x * 64, n0 = blockIdx.y * 64;
    int t = threadIdx.x;
    int c = t & 63, rg = t >> 6;
#pragma unroll
    for (int i = 0; i < 16; i++) {
        int r = rg * 16 + i;
        T[r][c] = W[(size_t)(k0 + r) * N + n0 + c];
    }
    __syncthreads();
    int k = t & 63, ng = t >> 6;
#pragma unroll
    for (int i = 0; i < 16; i++) {
        int n = ng * 16 + i;
        Wt[(size_t)(n0 + n) * K + k0 + k] = f2b(T[k][n]);
    }
}

// ---------------------------------------------------------------------------
// Kernel 1: dual LayerNorm (skip f32, x_up f32) + window partition -> bf16.
// ---------------------------------------------------------------------------
__global__ __launch_bounds__(256) void k_lnprep(
    const float* __restrict__ skip, const float* __restrict__ xup,
    const float* __restrict__ g, const float* __restrict__ bta,
    u16* __restrict__ skW, u16* __restrict__ qW)
{
    int t = blockIdx.x * 4 + (threadIdx.x >> 6);
    int lane = threadIdx.x & 63;
    const float* ps = skip + (size_t)t * C_DIM;
    const float* px = xup + (size_t)t * C_DIM;
    float vs[6], vx[6];
    float s1 = 0.f, s2 = 0.f, x1 = 0.f, x2 = 0.f;
#pragma unroll
    for (int j = 0; j < 6; j++) {
        float a = ps[lane + j * 64];
        float b = px[lane + j * 64];
        vs[j] = a; vx[j] = b;
        s1 += a; s2 += a * a; x1 += b; x2 += b * b;
    }
#pragma unroll
    for (int off = 32; off; off >>= 1) {
        s1 += __shfl_xor(s1, off);
        s2 += __shfl_xor(s2, off);
        x1 += __shfl_xor(x1, off);
        x2 += __shfl_xor(x2, off);
    }
    float ms = s1 * (1.f / 384.f), mx = x1 * (1.f / 384.f);
    float rs = rsqrtf(fmaxf(s2 * (1.f / 384.f) - ms * ms, 0.f) + 1e-5f);
    float rx = rsqrtf(fmaxf(x2 * (1.f / 384.f) - mx * mx, 0.f) + 1e-5f);
    int d = t / 784, rem = t % 784, hh = rem / 28, ww = rem % 28;
    int win = (d / 7) * 16 + (hh / 7) * 4 + (ww / 7);
    int n = (d % 7) * 49 + (hh % 7) * 7 + (ww % 7);
    size_t dst = ((size_t)(win * NTOK + n)) * C_DIM + lane;
#pragma unroll
    for (int j = 0; j < 6; j++) {
        int c = lane + j * 64;
        float gg = g[c], bb = bta[c];
        skW[dst + j * 64] = f2b((vs[j] - ms) * rs * gg + bb);
        qW[dst + j * 64]  = f2b((vx[j] - mx) * rx * gg + bb);
    }
}

// ---------------------------------------------------------------------------
// Kernel 5: LayerNorm of x2 (bf16) -> lnx (bf16), token layout.
// ---------------------------------------------------------------------------
__global__ __launch_bounds__(256) void k_ln2(
    const u16* __restrict__ x2, const float* __restrict__ g,
    const float* __restrict__ bta, u16* __restrict__ lnx)
{
    int t = blockIdx.x * 4 + (threadIdx.x >> 6);
    int lane = threadIdx.x & 63;
    const u16* p = x2 + (size_t)t * C_DIM;
    float v[6];
    float s1 = 0.f, s2 = 0.f;
#pragma unroll
    for (int j = 0; j < 6; j++) {
        float a = u2f(p[lane + j * 64]);
        v[j] = a; s1 += a; s2 += a * a;
    }
#pragma unroll
    for (int off = 32; off; off >>= 1) {
        s1 += __shfl_xor(s1, off);
        s2 += __shfl_xor(s2, off);
    }
    float m = s1 * (1.f / 384.f);
    float r = rsqrtf(fmaxf(s2 * (1.f / 384.f) - m * m, 0.f) + 1e-5f);
    size_t dst = (size_t)t * C_DIM + lane;
#pragma unroll
    for (int j = 0; j < 6; j++) {
        int c = lane + j * 64;
        lnx[dst + j * 64] = f2b((v[j] - m) * r * g[c] + bta[c]);
    }
}

// ---------------------------------------------------------------------------
// MFMA GEMM core: C[64x64] = A[64xK] * Bt[64xK]^T, bf16 in, f32 acc.
// 256 threads = 4 waves; wave w computes rows [w*16, w*16+16) x 64 cols.
// BK=32 per iter: per wave 1 A-frag + 4 B-frags (ds_read_b128) + 4 MFMA.
// LDS pad 24 u16: row stride 112 B -> 16B-aligned b128, 2-way banks (free).
// ---------------------------------------------------------------------------
#define LDSW 56   // 32 data + 24 pad (u16)

__device__ __forceinline__ void gemm_mfma(
    const u16* __restrict__ A, const u16* __restrict__ Bt, int K,
    int rowBase, int colBase, int tid,
    u16 (*As)[LDSW], u16 (*Bs)[LDSW], f32x4 acc[4])
{
    const int srow = tid >> 2;        // 0..63  (staging row)
    const int scg  = tid & 3;         // 0..3   (staging 8-elem group)
    const int lane = tid & 63, wv = tid >> 6;
    const int m16 = lane & 15, quad = lane >> 4;

    uint4 a = *(const uint4*)(A + (size_t)(rowBase + srow) * K + scg * 8);
    uint4 b = *(const uint4*)(Bt + (size_t)(colBase + srow) * K + scg * 8);

    for (int kk = 0; kk < K; kk += 32) {
        *(uint4*)&As[srow][scg * 8] = a;
        *(uint4*)&Bs[srow][scg * 8] = b;
        __syncthreads();
        if (kk + 32 < K) {
            a = *(const uint4*)(A + (size_t)(rowBase + srow) * K + kk + 32 + scg * 8);
            b = *(const uint4*)(Bt + (size_t)(colBase + srow) * K + kk + 32 + scg * 8);
        }
        s16x8 af = *(const s16x8*)&As[wv * 16 + m16][quad * 8];
#pragma unroll
        for (int nb = 0; nb < 4; nb++) {
            s16x8 bf = *(const s16x8*)&Bs[nb * 16 + m16][quad * 8];
            acc[nb] = __builtin_amdgcn_mfma_f32_16x16x32_bf16(af, bf, acc[nb], 0, 0, 0);
        }
        __syncthreads();
    }
}

// Epilogue index helpers: for wave wv, quad, reg -> tile row; nb, n16 -> tile col.
#define EPI_SETUP \
    int lane = tid & 63, wv = tid >> 6, quad = lane >> 4, n16 = lane & 15;

// GEMM variant: KV projection (K=384, N=768), scatter to K/V (w,head,n,d) bf16.
__global__ __launch_bounds__(256) void k_gemm_kv(
    const u16* __restrict__ A, const u16* __restrict__ Wt, const float* __restrict__ bias,
    u16* __restrict__ Kb, u16* __restrict__ Vb)
{
    __shared__ __align__(16) u16 As[64][LDSW];
    __shared__ __align__(16) u16 Bs[64][LDSW];
    f32x4 acc[4] = {};
    int tid = threadIdx.x;
    int rowBase = blockIdx.x * 64, colBase = blockIdx.y * 64;
    gemm_mfma(A, Wt, 384, rowBase, colBase, tid, As, Bs, acc);
    EPI_SETUP
#pragma unroll
    for (int nb = 0; nb < 4; nb++) {
        int col = colBase + nb * 16 + n16;
        float bcol = bias[col];
        int isv = col >= 384;
        int remc = col - (isv ? 384 : 0);
        int hh = remc >> 5, dd = remc & 31;
#pragma unroll
        for (int reg = 0; reg < 4; reg++) {
            int r = rowBase + wv * 16 + quad * 4 + reg;
            int w = r / NTOK, nn = r % NTOK;
            size_t dst = ((size_t)((w * NHEAD + hh) * NTOK + nn)) * HD + dd;
            (isv ? Vb : Kb)[dst] = f2b(acc[nb][reg] + bcol);
        }
    }
}

// GEMM variant: output projection (K=384,N=384) + bias + residual(skip+xup f32) -> x2 bf16.
__global__ __launch_bounds__(256) void k_gemm_proj(
    const u16* __restrict__ A, const u16* __restrict__ Wt, const float* __restrict__ bias,
    const float* __restrict__ skip, const float* __restrict__ xup, u16* __restrict__ x2)
{
    __shared__ __align__(16) u16 As[64][LDSW];
    __shared__ __align__(16) u16 Bs[64][LDSW];
    f32x4 acc[4] = {};
    int tid = threadIdx.x;
    int rowBase = blockIdx.x * 64, colBase = blockIdx.y * 64;
    gemm_mfma(A, Wt, 384, rowBase, colBase, tid, As, Bs, acc);
    EPI_SETUP
#pragma unroll
    for (int nb = 0; nb < 4; nb++) {
        int col = colBase + nb * 16 + n16;
        float bcol = bias[col];
#pragma unroll
        for (int reg = 0; reg < 4; reg++) {
            size_t r = rowBase + wv * 16 + quad * 4 + reg;
            size_t idx = r * C_DIM + col;
            x2[idx] = f2b(acc[nb][reg] + bcol + skip[idx] + xup[idx]);
        }
    }
}

// GEMM variant: MLP1 (K=384,N=1536) + bias + gelu -> h1 chunk bf16 (local rows).
__global__ __launch_bounds__(256) void k_gemm_mlp1(
    const u16* __restrict__ A, const u16* __restrict__ Wt, const float* __restrict__ bias,
    u16* __restrict__ h1c, int rowOfs)
{
    __shared__ __align__(16) u16 As[64][LDSW];
    __shared__ __align__(16) u16 Bs[64][LDSW];
    f32x4 acc[4] = {};
    int tid = threadIdx.x;
    int rowBase = rowOfs + blockIdx.x * 64, colBase = blockIdx.y * 64;
    gemm_mfma(A, Wt, 384, rowBase, colBase, tid, As, Bs, acc);
    EPI_SETUP
#pragma unroll
    for (int nb = 0; nb < 4; nb++) {
        int col = colBase + nb * 16 + n16;
        float bcol = bias[col];
#pragma unroll
        for (int reg = 0; reg < 4; reg++) {
            size_t rl = (size_t)(rowBase - rowOfs) + wv * 16 + quad * 4 + reg;
            h1c[rl * 1536 + col] = f2b(gelu_tanh(acc[nb][reg] + bcol));
        }
    }
}

// GEMM variant: MLP2 (K=1536,N=384) + bias + residual x2 (bf16) -> out f32 (final).
__global__ __launch_bounds__(256) void k_gemm_mlp2(
    const u16* __restrict__ A, const u16* __restrict__ Wt, const float* __restrict__ bias,
    const u16* __restrict__ x2, float* __restrict__ out, int rowOfs)
{
    __shared__ __align__(16) u16 As[64][LDSW];
    __shared__ __align__(16) u16 Bs[64][LDSW];
    f32x4 acc[4] = {};
    int tid = threadIdx.x;
    int rowBase = blockIdx.x * 64, colBase = blockIdx.y * 64;   // local rows
    gemm_mfma(A, Wt, 1536, rowBase, colBase, tid, As, Bs, acc);
    EPI_SETUP
#pragma unroll
    for (int nb = 0; nb < 4; nb++) {
        int col = colBase + nb * 16 + n16;
        float bcol = bias[col];
#pragma unroll
        for (int reg = 0; reg < 4; reg++) {
            size_t rg = (size_t)rowOfs + rowBase + wv * 16 + quad * 4 + reg;
            size_t idx = rg * C_DIM + col;
            out[idx] = acc[nb][reg] + bcol + u2f(x2[idx]);
        }
    }
}

// ---------------------------------------------------------------------------
// Kernel 3: window attention. One block per (window, head); thread = query row.
// ---------------------------------------------------------------------------
__global__ __launch_bounds__(384) void k_attn(
    const u16* __restrict__ qW, const u16* __restrict__ Kb, const u16* __restrict__ Vb,
    const float* __restrict__ rpb, u16* __restrict__ oT)
{
    __shared__ __align__(16) u16 Ks[NTOK * HD];
    __shared__ __align__(16) u16 Vs[NTOK * HD];
    __shared__ float rp[2197];
    int w = blockIdx.x / NHEAD, h = blockIdx.x % NHEAD;
    int tid = threadIdx.x;
    size_t base = ((size_t)(w * NHEAD + h)) * NTOK * HD;
    for (int i = tid; i < NTOK * HD; i += 384) {
        Ks[i] = Kb[base + i];
        Vs[i] = Vb[base + i];
    }
    for (int i = tid; i < 2197; i += 384) rp[i] = rpb[i * NHEAD + h];
    __syncthreads();

    if (tid < NTOK) {
        int q = tid;
        int qz = q / 49, qy = (q / 7) % 7, qx = q % 7;
        float qr[32];
        const u16* qp = qW + ((size_t)(w * NTOK + q)) * C_DIM + h * HD;
#pragma unroll
        for (int d = 0; d < 32; d++) qr[d] = u2f(qp[d]) * 0.17677669529663687f;
        float m = -1e30f, l = 0.f, o[32];
#pragma unroll
        for (int d = 0; d < 32; d++) o[d] = 0.f;

        for (int k = 0; k < NTOK; k++) {
            int kz = k / 49, ky = (k / 7) % 7, kx = k % 7;
            float s = rp[(qz - kz + 6) * 169 + (qy - ky + 6) * 13 + (qx - kx + 6)];
            const uint4* kp = (const uint4*)(Ks + k * HD);
#pragma unroll
            for (int t4 = 0; t4 < 4; t4++) {
                uint4 u = kp[t4];
                int db = t4 * 8;
                s = fmaf(qr[db + 0], lof(u.x), s);
                s = fmaf(qr[db + 1], hif(u.x), s);
                s = fmaf(qr[db + 2], lof(u.y), s);
                s = fmaf(qr[db + 3], hif(u.y), s);
                s = fmaf(qr[db + 4], lof(u.z), s);
                s = fmaf(qr[db + 5], hif(u.z), s);
                s = fmaf(qr[db + 6], lof(u.w), s);
                s = fmaf(qr[db + 7], hif(u.w), s);
            }
            const uint4* vp = (const uint4*)(Vs + k * HD);
            if (s <= m) {
                float p = __expf(s - m);
                l += p;
#pragma unroll
                for (int t4 = 0; t4 < 4; t4++) {
                    uint4 u = vp[t4];
                    int db = t4 * 8;
                    o[db + 0] = fmaf(p, lof(u.x), o[db + 0]);
                    o[db + 1] = fmaf(p, hif(u.x), o[db + 1]);
                    o[db + 2] = fmaf(p, lof(u.y), o[db + 2]);
                    o[db + 3] = fmaf(p, hif(u.y), o[db + 3]);
                    o[db + 4] = fmaf(p, lof(u.z), o[db + 4]);
                    o[db + 5] = fmaf(p, hif(u.z), o[db + 5]);
                    o[db + 6] = fmaf(p, lof(u.w), o[db + 6]);
                    o[db + 7] = fmaf(p, hif(u.w), o[db + 7]);
                }
            } else {
                float rsc = __expf(m - s);
                m = s;
                l = fmaf(l, rsc, 1.f);
#pragma unroll
                for (int t4 = 0; t4 < 4; t4++) {
                    uint4 u = vp[t4];
                    int db = t4 * 8;
                    o[db + 0] = fmaf(o[db + 0], rsc, lof(u.x));
                    o[db + 1] = fmaf(o[db + 1], rsc, hif(u.x));
                    o[db + 2] = fmaf(o[db + 2], rsc, lof(u.y));
                    o[db + 3] = fmaf(o[db + 3], rsc, hif(u.y));
                    o[db + 4] = fmaf(o[db + 4], rsc, lof(u.z));
                    o[db + 5] = fmaf(o[db + 5], rsc, hif(u.z));
                    o[db + 6] = fmaf(o[db + 6], rsc, lof(u.w));
                    o[db + 7] = fmaf(o[db + 7], rsc, hif(u.w));
                }
            }
        }
        float rl = 1.f / l;
        int wd = w >> 4, wh = (w >> 2) & 3, wwi = w & 3;
        int gd = wd * 7 + qz, gh = wh * 7 + qy, gw = wwi * 7 + qx;
        size_t tok = ((size_t)gd * SIDE + gh) * SIDE + gw;
        u16* op = oT + tok * C_DIM + h * HD;
#pragma unroll
        for (int d = 0; d < 32; d++) op[d] = f2b(o[d] * rl);
    }
}

// ---------------------------------------------------------------------------
// Workspace: 4 x BUF (67.4 MB) + 3.24 MB bf16 transposed weights.
//   s0: skW -> oT     s1: qW -> x2     s2: Kb -> lnx     s3: Vb -> h1c
//   tail: kvWt(768x384) pWt(384x384) w1t(1536x384) w2t(384x1536)  [bf16, B^T]
// ---------------------------------------------------------------------------
extern "C" void kernel_launch(void* const* d_in, const int* in_sizes, int n_in,
                              void* d_out, int out_size, void* d_ws, size_t ws_size,
                              hipStream_t stream)
{
    const float* skip = (const float*)d_in[0];
    const float* xup  = (const float*)d_in[1];
    const float* ln1g = (const float*)d_in[5];
    const float* ln1b = (const float*)d_in[6];
    const float* kvw  = (const float*)d_in[7];
    const float* kvb  = (const float*)d_in[8];
    const float* rpb  = (const float*)d_in[9];
    const float* pw   = (const float*)d_in[10];
    const float* pb   = (const float*)d_in[11];
    const float* ln2g = (const float*)d_in[12];
    const float* ln2b = (const float*)d_in[13];
    const float* w1   = (const float*)d_in[14];
    const float* b1   = (const float*)d_in[15];
    const float* w2   = (const float*)d_in[16];
    const float* b2   = (const float*)d_in[17];
    float* out = (float*)d_out;

    char* ws = (char*)d_ws;
    const size_t BUFB = (size_t)LTOT * C_DIM * 2;   // 16,859,136 B
    u16* skW = (u16*)(ws);
    u16* qW  = (u16*)(ws + BUFB);
    u16* Kb  = (u16*)(ws + 2 * BUFB);
    u16* Vb  = (u16*)(ws + 3 * BUFB);
    u16* oT  = (u16*)(ws);                  // overlays skW (dead)
    u16* x2  = (u16*)(ws + BUFB);           // overlays qW (dead)
    u16* lnx = (u16*)(ws + 2 * BUFB);       // overlays Kb (dead)
    u16* h1c = (u16*)(ws + 3 * BUFB);       // overlays Vb (dead)
    char* wt = ws + 4 * BUFB;
    u16* kvWt = (u16*)(wt);                             // 768*384*2 = 589,824
    u16* pWt  = (u16*)(wt + 589824);                    // 384*384*2 = 294,912
    u16* w1t  = (u16*)(wt + 589824 + 294912);           // 1536*384*2 = 1,179,648
    u16* w2t  = (u16*)(wt + 589824 + 294912 + 1179648); // 384*1536*2 = 1,179,648

    // weight transposes (K x N -> N x K bf16)
    k_wt<<<dim3(6, 12), 256, 0, stream>>>(kvw, kvWt, 384, 768);
    k_wt<<<dim3(6, 6),  256, 0, stream>>>(pw,  pWt,  384, 384);
    k_wt<<<dim3(6, 24), 256, 0, stream>>>(w1,  w1t,  384, 1536);
    k_wt<<<dim3(24, 6), 256, 0, stream>>>(w2,  w2t,  1536, 384);

    k_lnprep<<<LTOT / 4, 256, 0, stream>>>(skip, xup, ln1g, ln1b, skW, qW);
    k_gemm_kv<<<dim3(343, 12), 256, 0, stream>>>(skW, kvWt, kvb, Kb, Vb);
    k_attn<<<NWIN * NHEAD, 384, 0, stream>>>(qW, Kb, Vb, rpb, oT);
    k_gemm_proj<<<dim3(343, 6), 256, 0, stream>>>(oT, pWt, pb, skip, xup, x2);
    k_ln2<<<LTOT / 4, 256, 0, stream>>>(x2, ln2g, ln2b, lnx);
    for (int c = 0; c < 7; c++) {
        int rowOfs = c * 3136;   // 49 blocks of 64 rows per chunk
        k_gemm_mlp1<<<dim3(49, 24), 256, 0, stream>>>(lnx, w1t, b1, h1c, rowOfs);
        k_gemm_mlp2<<<dim3(49, 6), 256, 0, stream>>>(h1c, w2t, b2, x2, out, rowOfs);
    }
}

// Round 6
// 717.967 us; speedup vs baseline: 2.7679x; 1.3390x over previous
//
#include <hip/hip_runtime.h>
#include <hip/hip_bf16.h>
#include <cstdint>

typedef unsigned short u16;
typedef short s16x8 __attribute__((ext_vector_type(8)));
typedef float f32x4 __attribute__((ext_vector_type(4)));

#define C_DIM 384
#define NHEAD 12
#define HD    32
#define NTOK  343     // tokens per window (7^3)
#define NWIN  64
#define LTOT  21952   // 28^3
#define SIDE  28

__device__ __forceinline__ float u2f(u16 u) {
    return __uint_as_float(((unsigned int)u) << 16);
}
__device__ __forceinline__ u16 f2b(float f) {
    unsigned int u = __float_as_uint(f);
    return (u16)((u + 0x7fffu + ((u >> 16) & 1u)) >> 16);   // RNE
}
__device__ __forceinline__ float gelu_tanh(float x) {
    float x3 = x * x * x;
    return 0.5f * x * (1.f + tanhf(0.7978845608028654f * (x + 0.044715f * x3)));
}

// ---------------------------------------------------------------------------
// Weight transpose + f32->bf16: Wt[n][k] = bf16(W[k][n]).  W is KxN row-major.
// ---------------------------------------------------------------------------
__global__ __launch_bounds__(256) void k_wt(
    const float* __restrict__ W, u16* __restrict__ Wt, int K, int N)
{
    __shared__ float T[64][65];
    int k0 = blockIdx.x * 64, n0 = blockIdx.y * 64;
    int t = threadIdx.x;
    int c = t & 63, rg = t >> 6;
#pragma unroll
    for (int i = 0; i < 16; i++) {
        int r = rg * 16 + i;
        T[r][c] = W[(size_t)(k0 + r) * N + n0 + c];
    }
    __syncthreads();
    int k = t & 63, ng = t >> 6;
#pragma unroll
    for (int i = 0; i < 16; i++) {
        int n = ng * 16 + i;
        Wt[(size_t)(n0 + n) * K + k0 + k] = f2b(T[k][n]);
    }
}

// ---------------------------------------------------------------------------
// Kernel 1: dual LayerNorm (skip f32, x_up f32) + window partition -> bf16.
// ---------------------------------------------------------------------------
__global__ __launch_bounds__(256) void k_lnprep(
    const float* __restrict__ skip, const float* __restrict__ xup,
    const float* __restrict__ g, const float* __restrict__ bta,
    u16* __restrict__ skW, u16* __restrict__ qW)
{
    int t = blockIdx.x * 4 + (threadIdx.x >> 6);
    int lane = threadIdx.x & 63;
    const float* ps = skip + (size_t)t * C_DIM;
    const float* px = xup + (size_t)t * C_DIM;
    float vs[6], vx[6];
    float s1 = 0.f, s2 = 0.f, x1 = 0.f, x2 = 0.f;
#pragma unroll
    for (int j = 0; j < 6; j++) {
        float a = ps[lane + j * 64];
        float b = px[lane + j * 64];
        vs[j] = a; vx[j] = b;
        s1 += a; s2 += a * a; x1 += b; x2 += b * b;
    }
#pragma unroll
    for (int off = 32; off; off >>= 1) {
        s1 += __shfl_xor(s1, off);
        s2 += __shfl_xor(s2, off);
        x1 += __shfl_xor(x1, off);
        x2 += __shfl_xor(x2, off);
    }
    float ms = s1 * (1.f / 384.f), mx = x1 * (1.f / 384.f);
    float rs = rsqrtf(fmaxf(s2 * (1.f / 384.f) - ms * ms, 0.f) + 1e-5f);
    float rx = rsqrtf(fmaxf(x2 * (1.f / 384.f) - mx * mx, 0.f) + 1e-5f);
    int d = t / 784, rem = t % 784, hh = rem / 28, ww = rem % 28;
    int win = (d / 7) * 16 + (hh / 7) * 4 + (ww / 7);
    int n = (d % 7) * 49 + (hh % 7) * 7 + (ww % 7);
    size_t dst = ((size_t)(win * NTOK + n)) * C_DIM + lane;
#pragma unroll
    for (int j = 0; j < 6; j++) {
        int c = lane + j * 64;
        float gg = g[c], bb = bta[c];
        skW[dst + j * 64] = f2b((vs[j] - ms) * rs * gg + bb);
        qW[dst + j * 64]  = f2b((vx[j] - mx) * rx * gg + bb);
    }
}

// ---------------------------------------------------------------------------
// Kernel 5: LayerNorm of x2 (bf16) -> lnx (bf16).
// ---------------------------------------------------------------------------
__global__ __launch_bounds__(256) void k_ln2(
    const u16* __restrict__ x2, const float* __restrict__ g,
    const float* __restrict__ bta, u16* __restrict__ lnx)
{
    int t = blockIdx.x * 4 + (threadIdx.x >> 6);
    int lane = threadIdx.x & 63;
    const u16* p = x2 + (size_t)t * C_DIM;
    float v[6];
    float s1 = 0.f, s2 = 0.f;
#pragma unroll
    for (int j = 0; j < 6; j++) {
        float a = u2f(p[lane + j * 64]);
        v[j] = a; s1 += a; s2 += a * a;
    }
#pragma unroll
    for (int off = 32; off; off >>= 1) {
        s1 += __shfl_xor(s1, off);
        s2 += __shfl_xor(s2, off);
    }
    float m = s1 * (1.f / 384.f);
    float r = rsqrtf(fmaxf(s2 * (1.f / 384.f) - m * m, 0.f) + 1e-5f);
    size_t dst = (size_t)t * C_DIM + lane;
#pragma unroll
    for (int j = 0; j < 6; j++) {
        int c = lane + j * 64;
        lnx[dst + j * 64] = f2b((v[j] - m) * r * g[c] + bta[c]);
    }
}

// ---------------------------------------------------------------------------
// MFMA GEMM core: C[64x64] = A[64xK] * Bt[64xK]^T, bf16 in, f32 acc.
// ---------------------------------------------------------------------------
#define LDSW 56   // 32 data + 24 pad (u16)

__device__ __forceinline__ void gemm_mfma(
    const u16* __restrict__ A, const u16* __restrict__ Bt, int K,
    int rowBase, int colBase, int tid,
    u16 (*As)[LDSW], u16 (*Bs)[LDSW], f32x4 acc[4])
{
    const int srow = tid >> 2;
    const int scg  = tid & 3;
    const int lane = tid & 63, wv = tid >> 6;
    const int m16 = lane & 15, quad = lane >> 4;

    uint4 a = *(const uint4*)(A + (size_t)(rowBase + srow) * K + scg * 8);
    uint4 b = *(const uint4*)(Bt + (size_t)(colBase + srow) * K + scg * 8);

    for (int kk = 0; kk < K; kk += 32) {
        *(uint4*)&As[srow][scg * 8] = a;
        *(uint4*)&Bs[srow][scg * 8] = b;
        __syncthreads();
        if (kk + 32 < K) {
            a = *(const uint4*)(A + (size_t)(rowBase + srow) * K + kk + 32 + scg * 8);
            b = *(const uint4*)(Bt + (size_t)(colBase + srow) * K + kk + 32 + scg * 8);
        }
        s16x8 af = *(const s16x8*)&As[wv * 16 + m16][quad * 8];
#pragma unroll
        for (int nb = 0; nb < 4; nb++) {
            s16x8 bf = *(const s16x8*)&Bs[nb * 16 + m16][quad * 8];
            acc[nb] = __builtin_amdgcn_mfma_f32_16x16x32_bf16(af, bf, acc[nb], 0, 0, 0);
        }
        __syncthreads();
    }
}

#define EPI_SETUP \
    int lane = tid & 63, wv = tid >> 6, quad = lane >> 4, n16 = lane & 15;

__global__ __launch_bounds__(256) void k_gemm_kv(
    const u16* __restrict__ A, const u16* __restrict__ Wt, const float* __restrict__ bias,
    u16* __restrict__ Kb, u16* __restrict__ Vb)
{
    __shared__ __align__(16) u16 As[64][LDSW];
    __shared__ __align__(16) u16 Bs[64][LDSW];
    f32x4 acc[4] = {};
    int tid = threadIdx.x;
    int rowBase = blockIdx.x * 64, colBase = blockIdx.y * 64;
    gemm_mfma(A, Wt, 384, rowBase, colBase, tid, As, Bs, acc);
    EPI_SETUP
#pragma unroll
    for (int nb = 0; nb < 4; nb++) {
        int col = colBase + nb * 16 + n16;
        float bcol = bias[col];
        int isv = col >= 384;
        int remc = col - (isv ? 384 : 0);
        int hh = remc >> 5, dd = remc & 31;
#pragma unroll
        for (int reg = 0; reg < 4; reg++) {
            int r = rowBase + wv * 16 + quad * 4 + reg;
            int w = r / NTOK, nn = r % NTOK;
            size_t dst = ((size_t)((w * NHEAD + hh) * NTOK + nn)) * HD + dd;
            (isv ? Vb : Kb)[dst] = f2b(acc[nb][reg] + bcol);
        }
    }
}

__global__ __launch_bounds__(256) void k_gemm_proj(
    const u16* __restrict__ A, const u16* __restrict__ Wt, const float* __restrict__ bias,
    const float* __restrict__ skip, const float* __restrict__ xup, u16* __restrict__ x2)
{
    __shared__ __align__(16) u16 As[64][LDSW];
    __shared__ __align__(16) u16 Bs[64][LDSW];
    f32x4 acc[4] = {};
    int tid = threadIdx.x;
    int rowBase = blockIdx.x * 64, colBase = blockIdx.y * 64;
    gemm_mfma(A, Wt, 384, rowBase, colBase, tid, As, Bs, acc);
    EPI_SETUP
#pragma unroll
    for (int nb = 0; nb < 4; nb++) {
        int col = colBase + nb * 16 + n16;
        float bcol = bias[col];
#pragma unroll
        for (int reg = 0; reg < 4; reg++) {
            size_t r = rowBase + wv * 16 + quad * 4 + reg;
            size_t idx = r * C_DIM + col;
            x2[idx] = f2b(acc[nb][reg] + bcol + skip[idx] + xup[idx]);
        }
    }
}

__global__ __launch_bounds__(256) void k_gemm_mlp1(
    const u16* __restrict__ A, const u16* __restrict__ Wt, const float* __restrict__ bias,
    u16* __restrict__ h1c, int rowOfs)
{
    __shared__ __align__(16) u16 As[64][LDSW];
    __shared__ __align__(16) u16 Bs[64][LDSW];
    f32x4 acc[4] = {};
    int tid = threadIdx.x;
    int rowBase = rowOfs + blockIdx.x * 64, colBase = blockIdx.y * 64;
    gemm_mfma(A, Wt, 384, rowBase, colBase, tid, As, Bs, acc);
    EPI_SETUP
#pragma unroll
    for (int nb = 0; nb < 4; nb++) {
        int col = colBase + nb * 16 + n16;
        float bcol = bias[col];
#pragma unroll
        for (int reg = 0; reg < 4; reg++) {
            size_t rl = (size_t)(rowBase - rowOfs) + wv * 16 + quad * 4 + reg;
            h1c[rl * 1536 + col] = f2b(gelu_tanh(acc[nb][reg] + bcol));
        }
    }
}

__global__ __launch_bounds__(256) void k_gemm_mlp2(
    const u16* __restrict__ A, const u16* __restrict__ Wt, const float* __restrict__ bias,
    const u16* __restrict__ x2, float* __restrict__ out, int rowOfs)
{
    __shared__ __align__(16) u16 As[64][LDSW];
    __shared__ __align__(16) u16 Bs[64][LDSW];
    f32x4 acc[4] = {};
    int tid = threadIdx.x;
    int rowBase = blockIdx.x * 64, colBase = blockIdx.y * 64;   // local rows
    gemm_mfma(A, Wt, 1536, rowBase, colBase, tid, As, Bs, acc);
    EPI_SETUP
#pragma unroll
    for (int nb = 0; nb < 4; nb++) {
        int col = colBase + nb * 16 + n16;
        float bcol = bias[col];
#pragma unroll
        for (int reg = 0; reg < 4; reg++) {
            size_t rg = (size_t)rowOfs + rowBase + wv * 16 + quad * 4 + reg;
            size_t idx = rg * C_DIM + col;
            out[idx] = acc[nb][reg] + bcol + u2f(x2[idx]);
        }
    }
}

// ---------------------------------------------------------------------------
// Kernel 3: MFMA flash attention. Block = (head, window), 256 thr = 4 waves.
// LDS: K [352][40] u16, Vt [32][360] u16 (V transposed), rp bf16 [2208],
//      code LUT [352] u16, P-transpose [4 waves][16][40] u16.  Total 61,440 B.
// ---------------------------------------------------------------------------
#define KP 40      // K row stride (u16)
#define VP 360     // Vt row stride (u16)

__global__ __launch_bounds__(256) void k_attn(
    const u16* __restrict__ qW, const u16* __restrict__ Kb, const u16* __restrict__ Vb,
    const float* __restrict__ rpb, u16* __restrict__ oT)
{
    __shared__ __align__(16) u16 Ks[352 * KP];      // 28160 B
    __shared__ __align__(16) u16 Vt[32 * VP];       // 23040 B
    __shared__ __align__(16) u16 rp16[2208];        //  4416 B
    __shared__ __align__(16) u16 code[352];         //   704 B
    __shared__ __align__(16) u16 Pb[4 * 16 * KP];   //  5120 B

    const int h = blockIdx.x, w = blockIdx.y;
    const int tid = threadIdx.x;
    const int lane = tid & 63, wv = tid >> 6;
    const int m16 = lane & 15, quad = lane >> 4;
    const size_t base = ((size_t)(w * NHEAD + h)) * NTOK * HD;

    // --- stage K: 352 rows x 32 u16 = 4 uint4 per row (FIXED: full coverage) ---
    for (int t = tid; t < 1408; t += 256) {
        int r = t >> 2, c = (t & 3) << 3;           // c in {0,8,16,24} u16
        uint4 u = make_uint4(0, 0, 0, 0);
        if (r < NTOK) u = *(const uint4*)(Kb + base + r * HD + c);
        *(uint4*)&Ks[r * KP + c] = u;
    }
    // --- stage V transposed ---
    for (int t = tid; t < 352 * 32; t += 256) {
        int r = t >> 5, d = t & 31;
        u16 v = (r < NTOK) ? Vb[base + t] : (u16)0;
        Vt[d * VP + r] = v;
    }
    // --- bias table (bf16) ---
    for (int t = tid; t < 2208; t += 256)
        rp16[t] = (t < 2197) ? f2b(rpb[t * NHEAD + h]) : (u16)0;
    // --- token code LUT: z*169 + y*13 + x ; pad -> 1098 ---
    for (int t = tid; t < 352; t += 256) {
        int z = t / 49, rem = t % 49, y = rem / 7, x = rem % 7;
        code[t] = (t < NTOK) ? (u16)(z * 169 + y * 13 + x) : (u16)1098;
    }
    __syncthreads();

    const float scale = 0.17677669529663687f;  // 1/sqrt(32)
    u16* myP = Pb + wv * 16 * KP;

    for (int qt = wv; qt < 22; qt += 4) {
        int qbase = qt * 16;
        s16x8 qf = *(const s16x8*)(qW + ((size_t)(w * NTOK + qbase + m16)) * C_DIM
                                       + h * HD + quad * 8);
        int qcv[4];
#pragma unroll
        for (int i = 0; i < 4; i++) qcv[i] = code[qbase + quad * 4 + i];

        f32x4 O0 = {}, O1 = {};
        float m[4] = {-1e30f, -1e30f, -1e30f, -1e30f};
        float l[4] = {};

        for (int ks = 0; ks < 11; ks++) {
            int kbase = ks * 32;
            int kt0 = kbase + m16, kt1 = kbase + 16 + m16;
            s16x8 kf0 = *(const s16x8*)&Ks[kt0 * KP + quad * 8];
            s16x8 kf1 = *(const s16x8*)&Ks[kt1 * KP + quad * 8];
            f32x4 z = {};
            f32x4 sA = __builtin_amdgcn_mfma_f32_16x16x32_bf16(qf, kf0, z, 0, 0, 0);
            f32x4 sB = __builtin_amdgcn_mfma_f32_16x16x32_bf16(qf, kf1, z, 0, 0, 0);
            int kc0 = code[kt0], kc1 = code[kt1];
            bool k1ok = kt1 < NTOK;
#pragma unroll
            for (int i = 0; i < 4; i++) {
                float sa = fmaf(sA[i], scale, u2f(rp16[qcv[i] - kc0 + 1098]));
                float sb = k1ok ? fmaf(sB[i], scale, u2f(rp16[qcv[i] - kc1 + 1098]))
                                : -1e30f;
                float vm = fmaxf(sa, sb);
                vm = fmaxf(vm, __shfl_xor(vm, 1));
                vm = fmaxf(vm, __shfl_xor(vm, 2));
                vm = fmaxf(vm, __shfl_xor(vm, 4));
                vm = fmaxf(vm, __shfl_xor(vm, 8));
                float mn = fmaxf(m[i], vm);
                float alpha = __expf(m[i] - mn);
                float pa = __expf(sa - mn);
                float pb = __expf(sb - mn);
                float rs = pa + pb;
                rs += __shfl_xor(rs, 1);
                rs += __shfl_xor(rs, 2);
                rs += __shfl_xor(rs, 4);
                rs += __shfl_xor(rs, 8);
                l[i] = fmaf(l[i], alpha, rs);
                m[i] = mn;
                O0[i] *= alpha; O1[i] *= alpha;
                int prow = quad * 4 + i;
                myP[prow * KP + m16]      = f2b(pa);
                myP[prow * KP + 16 + m16] = f2b(pb);
            }
            s16x8 pf = *(const s16x8*)&myP[m16 * KP + quad * 8];
            s16x8 vf0 = *(const s16x8*)&Vt[m16 * VP + kbase + quad * 8];
            s16x8 vf1 = *(const s16x8*)&Vt[(16 + m16) * VP + kbase + quad * 8];
            O0 = __builtin_amdgcn_mfma_f32_16x16x32_bf16(pf, vf0, O0, 0, 0, 0);
            O1 = __builtin_amdgcn_mfma_f32_16x16x32_bf16(pf, vf1, O1, 0, 0, 0);
        }

        // epilogue: normalize + window-reverse scatter
        int wd = w >> 4, wh = (w >> 2) & 3, wwi = w & 3;
#pragma unroll
        for (int i = 0; i < 4; i++) {
            int q = qbase + quad * 4 + i;
            if (q < NTOK) {
                float rl = 1.f / l[i];
                int qz = q / 49, qrem = q % 49, qy = qrem / 7, qx = qrem % 7;
                size_t tok = ((size_t)(wd * 7 + qz) * SIDE + (wh * 7 + qy)) * SIDE
                             + (wwi * 7 + qx);
                u16* op = oT + tok * C_DIM + h * HD;
                op[m16]      = f2b(O0[i] * rl);
                op[16 + m16] = f2b(O1[i] * rl);
            }
        }
    }
}

// ---------------------------------------------------------------------------
// Workspace: 4 x BUF (67.4 MB) + 3.24 MB bf16 transposed weights.
// ---------------------------------------------------------------------------
extern "C" void kernel_launch(void* const* d_in, const int* in_sizes, int n_in,
                              void* d_out, int out_size, void* d_ws, size_t ws_size,
                              hipStream_t stream)
{
    const float* skip = (const float*)d_in[0];
    const float* xup  = (const float*)d_in[1];
    const float* ln1g = (const float*)d_in[5];
    const float* ln1b = (const float*)d_in[6];
    const float* kvw  = (const float*)d_in[7];
    const float* kvb  = (const float*)d_in[8];
    const float* rpb  = (const float*)d_in[9];
    const float* pw   = (const float*)d_in[10];
    const float* pb   = (const float*)d_in[11];
    const float* ln2g = (const float*)d_in[12];
    const float* ln2b = (const float*)d_in[13];
    const float* w1   = (const float*)d_in[14];
    const float* b1   = (const float*)d_in[15];
    const float* w2   = (const float*)d_in[16];
    const float* b2   = (const float*)d_in[17];
    float* out = (float*)d_out;

    char* ws = (char*)d_ws;
    const size_t BUFB = (size_t)LTOT * C_DIM * 2;   // 16,859,136 B
    u16* skW = (u16*)(ws);
    u16* qW  = (u16*)(ws + BUFB);
    u16* Kb  = (u16*)(ws + 2 * BUFB);
    u16* Vb  = (u16*)(ws + 3 * BUFB);
    u16* oT  = (u16*)(ws);                  // overlays skW (dead)
    u16* x2  = (u16*)(ws + BUFB);           // overlays qW (dead)
    u16* lnx = (u16*)(ws + 2 * BUFB);       // overlays Kb (dead)
    u16* h1c = (u16*)(ws + 3 * BUFB);       // overlays Vb (dead)
    char* wt = ws + 4 * BUFB;
    u16* kvWt = (u16*)(wt);
    u16* pWt  = (u16*)(wt + 589824);
    u16* w1t  = (u16*)(wt + 589824 + 294912);
    u16* w2t  = (u16*)(wt + 589824 + 294912 + 1179648);

    k_wt<<<dim3(6, 12), 256, 0, stream>>>(kvw, kvWt, 384, 768);
    k_wt<<<dim3(6, 6),  256, 0, stream>>>(pw,  pWt,  384, 384);
    k_wt<<<dim3(6, 24), 256, 0, stream>>>(w1,  w1t,  384, 1536);
    k_wt<<<dim3(24, 6), 256, 0, stream>>>(w2,  w2t,  1536, 384);

    k_lnprep<<<LTOT / 4, 256, 0, stream>>>(skip, xup, ln1g, ln1b, skW, qW);
    k_gemm_kv<<<dim3(343, 12), 256, 0, stream>>>(skW, kvWt, kvb, Kb, Vb);
    k_attn<<<dim3(NHEAD, NWIN), 256, 0, stream>>>(qW, Kb, Vb, rpb, oT);
    k_gemm_proj<<<dim3(343, 6), 256, 0, stream>>>(oT, pWt, pb, skip, xup, x2);
    k_ln2<<<LTOT / 4, 256, 0, stream>>>(x2, ln2g, ln2b, lnx);
    for (int c = 0; c < 7; c++) {
        int rowOfs = c * 3136;
        k_gemm_mlp1<<<dim3(49, 24), 256, 0, stream>>>(lnx, w1t, b1, h1c, rowOfs);
        k_gemm_mlp2<<<dim3(49, 6), 256, 0, stream>>>(h1c, w2t, b2, x2, out, rowOfs);
    }
}

// Round 7
// 475.212 us; speedup vs baseline: 4.1818x; 1.5108x over previous
//
#include <hip/hip_runtime.h>
#include <hip/hip_bf16.h>
#include <cstdint>

typedef unsigned short u16;
typedef short s16x8 __attribute__((ext_vector_type(8)));
typedef float f32x4 __attribute__((ext_vector_type(4)));

#define C_DIM 384
#define NHEAD 12
#define HD    32
#define NTOK  343     // tokens per window (7^3)
#define NWIN  64
#define LTOT  21952   // 28^3
#define SIDE  28

__device__ __forceinline__ float u2f(u16 u) {
    return __uint_as_float(((unsigned int)u) << 16);
}
__device__ __forceinline__ u16 f2b(float f) {
    unsigned int u = __float_as_uint(f);
    return (u16)((u + 0x7fffu + ((u >> 16) & 1u)) >> 16);   // RNE
}
__device__ __forceinline__ float gelu_tanh(float x) {
    float x3 = x * x * x;
    return 0.5f * x * (1.f + tanhf(0.7978845608028654f * (x + 0.044715f * x3)));
}

// ---------------------------------------------------------------------------
// Weight transpose + f32->bf16: Wt[n][k] = bf16(W[k][n]).  W is KxN row-major.
// ---------------------------------------------------------------------------
__global__ __launch_bounds__(256) void k_wt(
    const float* __restrict__ W, u16* __restrict__ Wt, int K, int N)
{
    __shared__ float T[64][65];
    int k0 = blockIdx.x * 64, n0 = blockIdx.y * 64;
    int t = threadIdx.x;
    int c = t & 63, rg = t >> 6;
#pragma unroll
    for (int i = 0; i < 16; i++) {
        int r = rg * 16 + i;
        T[r][c] = W[(size_t)(k0 + r) * N + n0 + c];
    }
    __syncthreads();
    int k = t & 63, ng = t >> 6;
#pragma unroll
    for (int i = 0; i < 16; i++) {
        int n = ng * 16 + i;
        Wt[(size_t)(n0 + n) * K + k0 + k] = f2b(T[k][n]);
    }
}

// ---------------------------------------------------------------------------
// Kernel 1: dual LayerNorm (skip f32, x_up f32) + window partition -> bf16.
// ---------------------------------------------------------------------------
__global__ __launch_bounds__(256) void k_lnprep(
    const float* __restrict__ skip, const float* __restrict__ xup,
    const float* __restrict__ g, const float* __restrict__ bta,
    u16* __restrict__ skW, u16* __restrict__ qW)
{
    int t = blockIdx.x * 4 + (threadIdx.x >> 6);
    int lane = threadIdx.x & 63;
    const float* ps = skip + (size_t)t * C_DIM;
    const float* px = xup + (size_t)t * C_DIM;
    float vs[6], vx[6];
    float s1 = 0.f, s2 = 0.f, x1 = 0.f, x2 = 0.f;
#pragma unroll
    for (int j = 0; j < 6; j++) {
        float a = ps[lane + j * 64];
        float b = px[lane + j * 64];
        vs[j] = a; vx[j] = b;
        s1 += a; s2 += a * a; x1 += b; x2 += b * b;
    }
#pragma unroll
    for (int off = 32; off; off >>= 1) {
        s1 += __shfl_xor(s1, off);
        s2 += __shfl_xor(s2, off);
        x1 += __shfl_xor(x1, off);
        x2 += __shfl_xor(x2, off);
    }
    float ms = s1 * (1.f / 384.f), mx = x1 * (1.f / 384.f);
    float rs = rsqrtf(fmaxf(s2 * (1.f / 384.f) - ms * ms, 0.f) + 1e-5f);
    float rx = rsqrtf(fmaxf(x2 * (1.f / 384.f) - mx * mx, 0.f) + 1e-5f);
    int d = t / 784, rem = t % 784, hh = rem / 28, ww = rem % 28;
    int win = (d / 7) * 16 + (hh / 7) * 4 + (ww / 7);
    int n = (d % 7) * 49 + (hh % 7) * 7 + (ww % 7);
    size_t dst = ((size_t)(win * NTOK + n)) * C_DIM + lane;
#pragma unroll
    for (int j = 0; j < 6; j++) {
        int c = lane + j * 64;
        float gg = g[c], bb = bta[c];
        skW[dst + j * 64] = f2b((vs[j] - ms) * rs * gg + bb);
        qW[dst + j * 64]  = f2b((vx[j] - mx) * rx * gg + bb);
    }
}

// ---------------------------------------------------------------------------
// Kernel 5: LayerNorm of x2 (bf16) -> lnx (bf16).
// ---------------------------------------------------------------------------
__global__ __launch_bounds__(256) void k_ln2(
    const u16* __restrict__ x2, const float* __restrict__ g,
    const float* __restrict__ bta, u16* __restrict__ lnx)
{
    int t = blockIdx.x * 4 + (threadIdx.x >> 6);
    int lane = threadIdx.x & 63;
    const u16* p = x2 + (size_t)t * C_DIM;
    float v[6];
    float s1 = 0.f, s2 = 0.f;
#pragma unroll
    for (int j = 0; j < 6; j++) {
        float a = u2f(p[lane + j * 64]);
        v[j] = a; s1 += a; s2 += a * a;
    }
#pragma unroll
    for (int off = 32; off; off >>= 1) {
        s1 += __shfl_xor(s1, off);
        s2 += __shfl_xor(s2, off);
    }
    float m = s1 * (1.f / 384.f);
    float r = rsqrtf(fmaxf(s2 * (1.f / 384.f) - m * m, 0.f) + 1e-5f);
    size_t dst = (size_t)t * C_DIM + lane;
#pragma unroll
    for (int j = 0; j < 6; j++) {
        int c = lane + j * 64;
        lnx[dst + j * 64] = f2b((v[j] - m) * r * g[c] + bta[c]);
    }
}

// ---------------------------------------------------------------------------
// MFMA GEMM core: C[64x64] = A[64xK] * Bt[64xK]^T, bf16 in, f32 acc.
// ---------------------------------------------------------------------------
#define LDSW 56   // 32 data + 24 pad (u16)

__device__ __forceinline__ void gemm_mfma(
    const u16* __restrict__ A, const u16* __restrict__ Bt, int K,
    int rowBase, int colBase, int tid,
    u16 (*As)[LDSW], u16 (*Bs)[LDSW], f32x4 acc[4])
{
    const int srow = tid >> 2;
    const int scg  = tid & 3;
    const int lane = tid & 63, wv = tid >> 6;
    const int m16 = lane & 15, quad = lane >> 4;

    uint4 a = *(const uint4*)(A + (size_t)(rowBase + srow) * K + scg * 8);
    uint4 b = *(const uint4*)(Bt + (size_t)(colBase + srow) * K + scg * 8);

    for (int kk = 0; kk < K; kk += 32) {
        *(uint4*)&As[srow][scg * 8] = a;
        *(uint4*)&Bs[srow][scg * 8] = b;
        __syncthreads();
        if (kk + 32 < K) {
            a = *(const uint4*)(A + (size_t)(rowBase + srow) * K + kk + 32 + scg * 8);
            b = *(const uint4*)(Bt + (size_t)(colBase + srow) * K + kk + 32 + scg * 8);
        }
        s16x8 af = *(const s16x8*)&As[wv * 16 + m16][quad * 8];
#pragma unroll
        for (int nb = 0; nb < 4; nb++) {
            s16x8 bf = *(const s16x8*)&Bs[nb * 16 + m16][quad * 8];
            acc[nb] = __builtin_amdgcn_mfma_f32_16x16x32_bf16(af, bf, acc[nb], 0, 0, 0);
        }
        __syncthreads();
    }
}

#define EPI_SETUP \
    int lane = tid & 63, wv = tid >> 6, quad = lane >> 4, n16 = lane & 15;

__global__ __launch_bounds__(256) void k_gemm_kv(
    const u16* __restrict__ A, const u16* __restrict__ Wt, const float* __restrict__ bias,
    u16* __restrict__ Kb, u16* __restrict__ Vb)
{
    __shared__ __align__(16) u16 As[64][LDSW];
    __shared__ __align__(16) u16 Bs[64][LDSW];
    f32x4 acc[4] = {};
    int tid = threadIdx.x;
    int rowBase = blockIdx.x * 64, colBase = blockIdx.y * 64;
    gemm_mfma(A, Wt, 384, rowBase, colBase, tid, As, Bs, acc);
    EPI_SETUP
#pragma unroll
    for (int nb = 0; nb < 4; nb++) {
        int col = colBase + nb * 16 + n16;
        float bcol = bias[col];
        int isv = col >= 384;
        int remc = col - (isv ? 384 : 0);
        int hh = remc >> 5, dd = remc & 31;
#pragma unroll
        for (int reg = 0; reg < 4; reg++) {
            int r = rowBase + wv * 16 + quad * 4 + reg;
            int w = r / NTOK, nn = r % NTOK;
            size_t dst = ((size_t)((w * NHEAD + hh) * NTOK + nn)) * HD + dd;
            (isv ? Vb : Kb)[dst] = f2b(acc[nb][reg] + bcol);
        }
    }
}

__global__ __launch_bounds__(256) void k_gemm_proj(
    const u16* __restrict__ A, const u16* __restrict__ Wt, const float* __restrict__ bias,
    const float* __restrict__ skip, const float* __restrict__ xup, u16* __restrict__ x2)
{
    __shared__ __align__(16) u16 As[64][LDSW];
    __shared__ __align__(16) u16 Bs[64][LDSW];
    f32x4 acc[4] = {};
    int tid = threadIdx.x;
    int rowBase = blockIdx.x * 64, colBase = blockIdx.y * 64;
    gemm_mfma(A, Wt, 384, rowBase, colBase, tid, As, Bs, acc);
    EPI_SETUP
#pragma unroll
    for (int nb = 0; nb < 4; nb++) {
        int col = colBase + nb * 16 + n16;
        float bcol = bias[col];
#pragma unroll
        for (int reg = 0; reg < 4; reg++) {
            size_t r = rowBase + wv * 16 + quad * 4 + reg;
            size_t idx = r * C_DIM + col;
            x2[idx] = f2b(acc[nb][reg] + bcol + skip[idx] + xup[idx]);
        }
    }
}

__global__ __launch_bounds__(256) void k_gemm_mlp1(
    const u16* __restrict__ A, const u16* __restrict__ Wt, const float* __restrict__ bias,
    u16* __restrict__ h1c, int rowOfs)
{
    __shared__ __align__(16) u16 As[64][LDSW];
    __shared__ __align__(16) u16 Bs[64][LDSW];
    f32x4 acc[4] = {};
    int tid = threadIdx.x;
    int rowBase = rowOfs + blockIdx.x * 64, colBase = blockIdx.y * 64;
    gemm_mfma(A, Wt, 384, rowBase, colBase, tid, As, Bs, acc);
    EPI_SETUP
#pragma unroll
    for (int nb = 0; nb < 4; nb++) {
        int col = colBase + nb * 16 + n16;
        float bcol = bias[col];
#pragma unroll
        for (int reg = 0; reg < 4; reg++) {
            size_t rl = (size_t)(rowBase - rowOfs) + wv * 16 + quad * 4 + reg;
            h1c[rl * 1536 + col] = f2b(gelu_tanh(acc[nb][reg] + bcol));
        }
    }
}

__global__ __launch_bounds__(256) void k_gemm_mlp2(
    const u16* __restrict__ A, const u16* __restrict__ Wt, const float* __restrict__ bias,
    const u16* __restrict__ x2, float* __restrict__ out, int rowOfs)
{
    __shared__ __align__(16) u16 As[64][LDSW];
    __shared__ __align__(16) u16 Bs[64][LDSW];
    f32x4 acc[4] = {};
    int tid = threadIdx.x;
    int rowBase = blockIdx.x * 64, colBase = blockIdx.y * 64;   // local rows
    gemm_mfma(A, Wt, 1536, rowBase, colBase, tid, As, Bs, acc);
    EPI_SETUP
#pragma unroll
    for (int nb = 0; nb < 4; nb++) {
        int col = colBase + nb * 16 + n16;
        float bcol = bias[col];
#pragma unroll
        for (int reg = 0; reg < 4; reg++) {
            size_t rg = (size_t)rowOfs + rowBase + wv * 16 + quad * 4 + reg;
            size_t idx = rg * C_DIM + col;
            out[idx] = acc[nb][reg] + bcol + u2f(x2[idx]);
        }
    }
}

// ---------------------------------------------------------------------------
// Kernel 3: MFMA flash attention, two-pass softmax, S in registers.
// Block = (head, window, half); 256 thr = 4 waves; each half does 11 q-tiles.
// Pass 1: 22 S-MFMAs into regs (scale+bias folded), per-lane max only.
// Pass 2: exp, per-lane l, P->LDS->A-frag, PV-MFMA.  No per-step shuffles.
// ---------------------------------------------------------------------------
#define KP 40      // K / P row stride (u16)
#define VP 360     // Vt row stride (u16)

__global__ __launch_bounds__(256, 2) void k_attn(
    const u16* __restrict__ qW, const u16* __restrict__ Kb, const u16* __restrict__ Vb,
    const float* __restrict__ rpb, u16* __restrict__ oT)
{
    __shared__ __align__(16) u16 Ks[352 * KP];      // 28160 B
    __shared__ __align__(16) u16 Vt[32 * VP];       // 23040 B
    __shared__ __align__(16) u16 rp16[2208];        //  4416 B
    __shared__ __align__(16) u16 code[352];         //   704 B
    __shared__ __align__(16) u16 Pb[4 * 16 * KP];   //  5120 B

    const int h = blockIdx.x, w = blockIdx.y, half = blockIdx.z;
    const int tid = threadIdx.x;
    const int lane = tid & 63, wv = tid >> 6;
    const int m16 = lane & 15, quad = lane >> 4;
    const size_t base = ((size_t)(w * NHEAD + h)) * NTOK * HD;

    // --- stage K: 352 rows x 32 u16 = 4 uint4 per row ---
    for (int t = tid; t < 1408; t += 256) {
        int r = t >> 2, c = (t & 3) << 3;
        uint4 u = make_uint4(0, 0, 0, 0);
        if (r < NTOK) u = *(const uint4*)(Kb + base + r * HD + c);
        *(uint4*)&Ks[r * KP + c] = u;
    }
    // --- stage V transposed; consecutive lanes write consecutive n (no conflicts)
    for (int t = tid; t < 1408; t += 256) {
        int dg = t / 352, n = t - dg * 352;     // dg 0..3 (8 d each), n 0..351
        uint4 u = make_uint4(0, 0, 0, 0);
        if (n < NTOK) u = *(const uint4*)(Vb + base + n * HD + dg * 8);
        int d0 = dg * 8;
        Vt[(d0 + 0) * VP + n] = (u16)(u.x & 0xffff);
        Vt[(d0 + 1) * VP + n] = (u16)(u.x >> 16);
        Vt[(d0 + 2) * VP + n] = (u16)(u.y & 0xffff);
        Vt[(d0 + 3) * VP + n] = (u16)(u.y >> 16);
        Vt[(d0 + 4) * VP + n] = (u16)(u.z & 0xffff);
        Vt[(d0 + 5) * VP + n] = (u16)(u.z >> 16);
        Vt[(d0 + 6) * VP + n] = (u16)(u.w & 0xffff);
        Vt[(d0 + 7) * VP + n] = (u16)(u.w >> 16);
    }
    // --- bias table (bf16) ---
    for (int t = tid; t < 2208; t += 256)
        rp16[t] = (t < 2197) ? f2b(rpb[t * NHEAD + h]) : (u16)0;
    // --- token code LUT: z*169 + y*13 + x ; pad -> 1098 ---
    for (int t = tid; t < 352; t += 256) {
        int z = t / 49, rem = t % 49, y = rem / 7, x = rem % 7;
        code[t] = (t < NTOK) ? (u16)(z * 169 + y * 13 + x) : (u16)1098;
    }
    __syncthreads();

    const float scale = 0.17677669529663687f;  // 1/sqrt(32)
    u16* myP = Pb + wv * 16 * KP;

    for (int qt = half * 11 + wv; qt < half * 11 + 11; qt += 4) {
        int qbase = qt * 16;
        int qrow = min(qbase + m16, NTOK - 1);
        s16x8 qf = *(const s16x8*)(qW + ((size_t)(w * NTOK + qrow)) * C_DIM
                                       + h * HD + quad * 8);
        int qcv[4];
#pragma unroll
        for (int i = 0; i < 4; i++) qcv[i] = code[qbase + quad * 4 + i];

        f32x4 S0[11], S1[11];
        float mx[4] = {-1e30f, -1e30f, -1e30f, -1e30f};

        // ---- pass 1: all S tiles into registers, per-lane max ----
#pragma unroll
        for (int ks = 0; ks < 11; ks++) {
            int kbase = ks * 32;
            int kt0 = kbase + m16, kt1 = kt0 + 16;
            s16x8 kf0 = *(const s16x8*)&Ks[kt0 * KP + quad * 8];
            s16x8 kf1 = *(const s16x8*)&Ks[kt1 * KP + quad * 8];
            f32x4 z = {0.f, 0.f, 0.f, 0.f};
            f32x4 sA = __builtin_amdgcn_mfma_f32_16x16x32_bf16(qf, kf0, z, 0, 0, 0);
            f32x4 sB = __builtin_amdgcn_mfma_f32_16x16x32_bf16(qf, kf1, z, 0, 0, 0);
            int kc0 = code[kt0], kc1 = code[kt1];
            bool k1ok = (ks < 10) || (kt1 < NTOK);
#pragma unroll
            for (int i = 0; i < 4; i++) {
                float b0 = u2f(rp16[qcv[i] - kc0 + 1098]);
                float b1 = u2f(rp16[qcv[i] - kc1 + 1098]);
                float sa = fmaf(sA[i], scale, b0);
                float sb = k1ok ? fmaf(sB[i], scale, b1) : -1e30f;
                S0[ks][i] = sa;
                S1[ks][i] = sb;
                mx[i] = fmaxf(mx[i], fmaxf(sa, sb));
            }
        }
        // ---- row-max reduce (once per tile) ----
#pragma unroll
        for (int i = 0; i < 4; i++) {
            float v = mx[i];
            v = fmaxf(v, __shfl_xor(v, 1));
            v = fmaxf(v, __shfl_xor(v, 2));
            v = fmaxf(v, __shfl_xor(v, 4));
            v = fmaxf(v, __shfl_xor(v, 8));
            mx[i] = v;
        }

        // ---- pass 2: exp, per-lane l, PV ----
        f32x4 O0 = {}, O1 = {};
        float l[4] = {};
#pragma unroll
        for (int ks = 0; ks < 11; ks++) {
            int kbase = ks * 32;
#pragma unroll
            for (int i = 0; i < 4; i++) {
                float pa = __expf(S0[ks][i] - mx[i]);
                float pb = __expf(S1[ks][i] - mx[i]);
                l[i] += pa + pb;
                int prow = quad * 4 + i;
                myP[prow * KP + m16]      = f2b(pa);
                myP[prow * KP + 16 + m16] = f2b(pb);
            }
            s16x8 pf  = *(const s16x8*)&myP[m16 * KP + quad * 8];
            s16x8 vf0 = *(const s16x8*)&Vt[m16 * VP + kbase + quad * 8];
            s16x8 vf1 = *(const s16x8*)&Vt[(16 + m16) * VP + kbase + quad * 8];
            O0 = __builtin_amdgcn_mfma_f32_16x16x32_bf16(pf, vf0, O0, 0, 0, 0);
            O1 = __builtin_amdgcn_mfma_f32_16x16x32_bf16(pf, vf1, O1, 0, 0, 0);
        }
        // ---- l reduce (once per tile) ----
#pragma unroll
        for (int i = 0; i < 4; i++) {
            float v = l[i];
            v += __shfl_xor(v, 1);
            v += __shfl_xor(v, 2);
            v += __shfl_xor(v, 4);
            v += __shfl_xor(v, 8);
            l[i] = v;
        }

        // epilogue: normalize + window-reverse scatter
        int wd = w >> 4, wh = (w >> 2) & 3, wwi = w & 3;
#pragma unroll
        for (int i = 0; i < 4; i++) {
            int q = qbase + quad * 4 + i;
            if (q < NTOK) {
                float rl = 1.f / l[i];
                int qz = q / 49, qrem = q % 49, qy = qrem / 7, qx = qrem % 7;
                size_t tok = ((size_t)(wd * 7 + qz) * SIDE + (wh * 7 + qy)) * SIDE
                             + (wwi * 7 + qx);
                u16* op = oT + tok * C_DIM + h * HD;
                op[m16]      = f2b(O0[i] * rl);
                op[16 + m16] = f2b(O1[i] * rl);
            }
        }
    }
}

// ---------------------------------------------------------------------------
// Workspace: 4 x BUF (67.4 MB) + 3.24 MB bf16 transposed weights [+ h1 tail].
// ---------------------------------------------------------------------------
extern "C" void kernel_launch(void* const* d_in, const int* in_sizes, int n_in,
                              void* d_out, int out_size, void* d_ws, size_t ws_size,
                              hipStream_t stream)
{
    const float* skip = (const float*)d_in[0];
    const float* xup  = (const float*)d_in[1];
    const float* ln1g = (const float*)d_in[5];
    const float* ln1b = (const float*)d_in[6];
    const float* kvw  = (const float*)d_in[7];
    const float* kvb  = (const float*)d_in[8];
    const float* rpb  = (const float*)d_in[9];
    const float* pw   = (const float*)d_in[10];
    const float* pb   = (const float*)d_in[11];
    const float* ln2g = (const float*)d_in[12];
    const float* ln2b = (const float*)d_in[13];
    const float* w1   = (const float*)d_in[14];
    const float* b1   = (const float*)d_in[15];
    const float* w2   = (const float*)d_in[16];
    const float* b2   = (const float*)d_in[17];
    float* out = (float*)d_out;

    char* ws = (char*)d_ws;
    const size_t BUFB = (size_t)LTOT * C_DIM * 2;   // 16,859,136 B
    const size_t WTB  = 589824 + 294912 + 1179648 + 1179648;  // 3,244,032 B
    u16* skW = (u16*)(ws);
    u16* qW  = (u16*)(ws + BUFB);
    u16* Kb  = (u16*)(ws + 2 * BUFB);
    u16* Vb  = (u16*)(ws + 3 * BUFB);
    u16* oT  = (u16*)(ws);                  // overlays skW (dead)
    u16* x2  = (u16*)(ws + BUFB);           // overlays qW (dead)
    u16* lnx = (u16*)(ws + 2 * BUFB);       // overlays Kb (dead)
    char* wt = ws + 4 * BUFB;
    u16* kvWt = (u16*)(wt);
    u16* pWt  = (u16*)(wt + 589824);
    u16* w1t  = (u16*)(wt + 589824 + 294912);
    u16* w2t  = (u16*)(wt + 589824 + 294912 + 1179648);

    // h1 chunk buffer: use workspace tail beyond 4*BUF+WT if available,
    // else fall back to s3 (Vb region, dead after attention) with 49-block chunks.
    const size_t used = 4 * BUFB + WTB;
    const size_t blkBytes = 64 * 1536 * 2;          // 196,608 B per 64-row block
    int chunkBlocks = 49;
    u16* h1c = (u16*)(ws + 3 * BUFB);               // fallback: s3
    if (ws_size > used) {
        int cap = (int)((ws_size - used) / blkBytes);
        if (cap >= 49) {
            chunkBlocks = cap < 343 ? cap : 343;
            h1c = (u16*)(ws + used);
        }
    }

    k_wt<<<dim3(6, 12), 256, 0, stream>>>(kvw, kvWt, 384, 768);
    k_wt<<<dim3(6, 6),  256, 0, stream>>>(pw,  pWt,  384, 384);
    k_wt<<<dim3(6, 24), 256, 0, stream>>>(w1,  w1t,  384, 1536);
    k_wt<<<dim3(24, 6), 256, 0, stream>>>(w2,  w2t,  1536, 384);

    k_lnprep<<<LTOT / 4, 256, 0, stream>>>(skip, xup, ln1g, ln1b, skW, qW);
    k_gemm_kv<<<dim3(343, 12), 256, 0, stream>>>(skW, kvWt, kvb, Kb, Vb);
    k_attn<<<dim3(NHEAD, NWIN, 2), 256, 0, stream>>>(qW, Kb, Vb, rpb, oT);
    k_gemm_proj<<<dim3(343, 6), 256, 0, stream>>>(oT, pWt, pb, skip, xup, x2);
    k_ln2<<<LTOT / 4, 256, 0, stream>>>(x2, ln2g, ln2b, lnx);
    for (int b0 = 0; b0 < 343; b0 += chunkBlocks) {
        int nb = (343 - b0) < chunkBlocks ? (343 - b0) : chunkBlocks;
        int rowOfs = b0 * 64;
        k_gemm_mlp1<<<dim3(nb, 24), 256, 0, stream>>>(lnx, w1t, b1, h1c, rowOfs);
        k_gemm_mlp2<<<dim3(nb, 6), 256, 0, stream>>>(h1c, w2t, b2, x2, out, rowOfs);
    }
}

// Round 8
// 473.782 us; speedup vs baseline: 4.1944x; 1.0030x over previous
//
#include <hip/hip_runtime.h>
#include <hip/hip_bf16.h>
#include <cstdint>

typedef unsigned short u16;
typedef short s16x8 __attribute__((ext_vector_type(8)));
typedef float f32x4 __attribute__((ext_vector_type(4)));

#define C_DIM 384
#define NHEAD 12
#define HD    32
#define NTOK  343     // tokens per window (7^3)
#define NWIN  64
#define LTOT  21952   // 28^3
#define SIDE  28

__device__ __forceinline__ float u2f(u16 u) {
    return __uint_as_float(((unsigned int)u) << 16);
}
__device__ __forceinline__ u16 f2b(float f) {
    unsigned int u = __float_as_uint(f);
    return (u16)((u + 0x7fffu + ((u >> 16) & 1u)) >> 16);   // RNE
}
// gelu tanh-approx via hw exp: 0.5x(1+tanh(z)) == x / (1 + e^{-2z})
__device__ __forceinline__ float gelu_fast(float x) {
    float z = 0.7978845608028654f * (x + 0.044715f * x * x * x);
    return x / (1.f + __expf(-2.f * z));
}

// ---------------------------------------------------------------------------
// Weight transpose + f32->bf16: Wt[n][k] = bf16(W[k][n]).  W is KxN row-major.
// ---------------------------------------------------------------------------
__global__ __launch_bounds__(256) void k_wt(
    const float* __restrict__ W, u16* __restrict__ Wt, int K, int N)
{
    __shared__ float T[64][65];
    int k0 = blockIdx.x * 64, n0 = blockIdx.y * 64;
    int t = threadIdx.x;
    int c = t & 63, rg = t >> 6;
#pragma unroll
    for (int i = 0; i < 16; i++) {
        int r = rg * 16 + i;
        T[r][c] = W[(size_t)(k0 + r) * N + n0 + c];
    }
    __syncthreads();
    int k = t & 63, ng = t >> 6;
#pragma unroll
    for (int i = 0; i < 16; i++) {
        int n = ng * 16 + i;
        Wt[(size_t)(n0 + n) * K + k0 + k] = f2b(T[k][n]);
    }
}

// ---------------------------------------------------------------------------
// Kernel 1: dual LayerNorm + window partition -> bf16; also res = bf16(skip+xup)
// in token layout (stored into d_out scratch, consumed by proj epilogue).
// ---------------------------------------------------------------------------
__global__ __launch_bounds__(256) void k_lnprep(
    const float* __restrict__ skip, const float* __restrict__ xup,
    const float* __restrict__ g, const float* __restrict__ bta,
    u16* __restrict__ skW, u16* __restrict__ qW, u16* __restrict__ res)
{
    int t = blockIdx.x * 4 + (threadIdx.x >> 6);
    int lane = threadIdx.x & 63;
    const float* ps = skip + (size_t)t * C_DIM;
    const float* px = xup + (size_t)t * C_DIM;
    float vs[6], vx[6];
    float s1 = 0.f, s2 = 0.f, x1 = 0.f, x2 = 0.f;
#pragma unroll
    for (int j = 0; j < 6; j++) {
        float a = ps[lane + j * 64];
        float b = px[lane + j * 64];
        vs[j] = a; vx[j] = b;
        s1 += a; s2 += a * a; x1 += b; x2 += b * b;
    }
#pragma unroll
    for (int off = 32; off; off >>= 1) {
        s1 += __shfl_xor(s1, off);
        s2 += __shfl_xor(s2, off);
        x1 += __shfl_xor(x1, off);
        x2 += __shfl_xor(x2, off);
    }
    float ms = s1 * (1.f / 384.f), mx = x1 * (1.f / 384.f);
    float rs = rsqrtf(fmaxf(s2 * (1.f / 384.f) - ms * ms, 0.f) + 1e-5f);
    float rx = rsqrtf(fmaxf(x2 * (1.f / 384.f) - mx * mx, 0.f) + 1e-5f);
    int d = t / 784, rem = t % 784, hh = rem / 28, ww = rem % 28;
    int win = (d / 7) * 16 + (hh / 7) * 4 + (ww / 7);
    int n = (d % 7) * 49 + (hh % 7) * 7 + (ww % 7);
    size_t dst = ((size_t)(win * NTOK + n)) * C_DIM + lane;
    size_t td  = (size_t)t * C_DIM + lane;
#pragma unroll
    for (int j = 0; j < 6; j++) {
        int c = lane + j * 64;
        float gg = g[c], bb = bta[c];
        skW[dst + j * 64] = f2b((vs[j] - ms) * rs * gg + bb);
        qW[dst + j * 64]  = f2b((vx[j] - mx) * rx * gg + bb);
        res[td + j * 64]  = f2b(vs[j] + vx[j]);
    }
}

// ---------------------------------------------------------------------------
// Kernel 5: LayerNorm of x2 (bf16) -> lnx (bf16).
// ---------------------------------------------------------------------------
__global__ __launch_bounds__(256) void k_ln2(
    const u16* __restrict__ x2, const float* __restrict__ g,
    const float* __restrict__ bta, u16* __restrict__ lnx)
{
    int t = blockIdx.x * 4 + (threadIdx.x >> 6);
    int lane = threadIdx.x & 63;
    const u16* p = x2 + (size_t)t * C_DIM;
    float v[6];
    float s1 = 0.f, s2 = 0.f;
#pragma unroll
    for (int j = 0; j < 6; j++) {
        float a = u2f(p[lane + j * 64]);
        v[j] = a; s1 += a; s2 += a * a;
    }
#pragma unroll
    for (int off = 32; off; off >>= 1) {
        s1 += __shfl_xor(s1, off);
        s2 += __shfl_xor(s2, off);
    }
    float m = s1 * (1.f / 384.f);
    float r = rsqrtf(fmaxf(s2 * (1.f / 384.f) - m * m, 0.f) + 1e-5f);
    size_t dst = (size_t)t * C_DIM + lane;
#pragma unroll
    for (int j = 0; j < 6; j++) {
        int c = lane + j * 64;
        lnx[dst + j * 64] = f2b((v[j] - m) * r * g[c] + bta[c]);
    }
}

// ---------------------------------------------------------------------------
// 128x128 MFMA GEMM core: C = A[128xK] * Bt[128xK]^T, bf16 in, f32 acc.
// 256 thr = 4 waves; wave wv computes rows [wv*32, wv*32+32) x 128 cols.
// Per BK=32 iter per wave: 2 A-frag + 8 B-frag ds_read_b128, 16 MFMA.
// A rows clamped to M (M=21952 not a multiple of 128); B rows always valid.
// ---------------------------------------------------------------------------
#define BPAD 40   // LDS row stride in u16 (32 data + 8 pad; 2-way banks)

__device__ __forceinline__ void gemm128(
    const u16* __restrict__ A, const u16* __restrict__ Bt, int K, int M,
    int rowBase, int colBase, int tid,
    u16 (*As)[BPAD], u16 (*Bs)[BPAD], f32x4 acc[2][8])
{
    const int sr  = tid >> 2;          // 0..63 staging row
    const int scg = (tid & 3) << 3;    // u16 col offset {0,8,16,24}
    const int lane = tid & 63, wv = tid >> 6;
    const int m16 = lane & 15, quad = lane >> 4;

    int ra0 = min(rowBase + sr, M - 1);
    int ra1 = min(rowBase + 64 + sr, M - 1);
    const u16* pa0 = A + (size_t)ra0 * K + scg;
    const u16* pa1 = A + (size_t)ra1 * K + scg;
    const u16* pb0 = Bt + (size_t)(colBase + sr) * K + scg;
    const u16* pb1 = Bt + (size_t)(colBase + 64 + sr) * K + scg;

    uint4 a0 = *(const uint4*)pa0, a1 = *(const uint4*)pa1;
    uint4 b0 = *(const uint4*)pb0, b1 = *(const uint4*)pb1;

    for (int kk = 0; kk < K; kk += 32) {
        *(uint4*)&As[sr][scg]      = a0;
        *(uint4*)&As[64 + sr][scg] = a1;
        *(uint4*)&Bs[sr][scg]      = b0;
        *(uint4*)&Bs[64 + sr][scg] = b1;
        __syncthreads();
        if (kk + 32 < K) {
            a0 = *(const uint4*)(pa0 + kk + 32);
            a1 = *(const uint4*)(pa1 + kk + 32);
            b0 = *(const uint4*)(pb0 + kk + 32);
            b1 = *(const uint4*)(pb1 + kk + 32);
        }
        s16x8 af0 = *(const s16x8*)&As[wv * 32 + m16][quad * 8];
        s16x8 af1 = *(const s16x8*)&As[wv * 32 + 16 + m16][quad * 8];
#pragma unroll
        for (int c = 0; c < 8; c++) {
            s16x8 bf = *(const s16x8*)&Bs[c * 16 + m16][quad * 8];
            acc[0][c] = __builtin_amdgcn_mfma_f32_16x16x32_bf16(af0, bf, acc[0][c], 0, 0, 0);
            acc[1][c] = __builtin_amdgcn_mfma_f32_16x16x32_bf16(af1, bf, acc[1][c], 0, 0, 0);
        }
        __syncthreads();
    }
}

// Epilogue indices: row = rowBase + wv*32 + rt*16 + quad*4 + reg,
//                   col = colBase + c*16 + n16.
#define EPI_SETUP \
    int lane = tid & 63, wv = tid >> 6, quad = lane >> 4, n16 = lane & 15;

// KV projection (K=384, N=768): scatter to K/V (w,head,n,d) bf16.
__global__ __launch_bounds__(256) void k_gemm_kv(
    const u16* __restrict__ A, const u16* __restrict__ Wt, const float* __restrict__ bias,
    u16* __restrict__ Kb, u16* __restrict__ Vb)
{
    __shared__ __align__(16) u16 As[128][BPAD];
    __shared__ __align__(16) u16 Bs[128][BPAD];
    f32x4 acc[2][8] = {};
    int tid = threadIdx.x;
    int rowBase = blockIdx.x * 128, colBase = blockIdx.y * 128;
    gemm128(A, Wt, 384, LTOT, rowBase, colBase, tid, As, Bs, acc);
    EPI_SETUP
#pragma unroll
    for (int c = 0; c < 8; c++) {
        int col = colBase + c * 16 + n16;
        float bcol = bias[col];
        int isv = col >= 384;
        int remc = col - (isv ? 384 : 0);
        int hh = remc >> 5, dd = remc & 31;
#pragma unroll
        for (int rt = 0; rt < 2; rt++)
#pragma unroll
        for (int reg = 0; reg < 4; reg++) {
            int r = rowBase + wv * 32 + rt * 16 + quad * 4 + reg;
            if (r < LTOT) {
                int w = r / NTOK, nn = r % NTOK;
                size_t dst = ((size_t)((w * NHEAD + hh) * NTOK + nn)) * HD + dd;
                (isv ? Vb : Kb)[dst] = f2b(acc[rt][c][reg] + bcol);
            }
        }
    }
}

// Output projection (K=384, N=384) + bias + residual res (bf16) -> x2 bf16.
__global__ __launch_bounds__(256) void k_gemm_proj(
    const u16* __restrict__ A, const u16* __restrict__ Wt, const float* __restrict__ bias,
    const u16* __restrict__ res, u16* __restrict__ x2)
{
    __shared__ __align__(16) u16 As[128][BPAD];
    __shared__ __align__(16) u16 Bs[128][BPAD];
    f32x4 acc[2][8] = {};
    int tid = threadIdx.x;
    int rowBase = blockIdx.x * 128, colBase = blockIdx.y * 128;
    gemm128(A, Wt, 384, LTOT, rowBase, colBase, tid, As, Bs, acc);
    EPI_SETUP
#pragma unroll
    for (int c = 0; c < 8; c++) {
        int col = colBase + c * 16 + n16;
        float bcol = bias[col];
#pragma unroll
        for (int rt = 0; rt < 2; rt++)
#pragma unroll
        for (int reg = 0; reg < 4; reg++) {
            int r = rowBase + wv * 32 + rt * 16 + quad * 4 + reg;
            if (r < LTOT) {
                size_t idx = (size_t)r * C_DIM + col;
                x2[idx] = f2b(acc[rt][c][reg] + bcol + u2f(res[idx]));
            }
        }
    }
}

// MLP1 (K=384, N=1536) + bias + gelu -> h1 chunk bf16 (local rows).
__global__ __launch_bounds__(256) void k_gemm_mlp1(
    const u16* __restrict__ A, const u16* __restrict__ Wt, const float* __restrict__ bias,
    u16* __restrict__ h1c, int rowOfs)
{
    __shared__ __align__(16) u16 As[128][BPAD];
    __shared__ __align__(16) u16 Bs[128][BPAD];
    f32x4 acc[2][8] = {};
    int tid = threadIdx.x;
    int rowBase = rowOfs + blockIdx.x * 128, colBase = blockIdx.y * 128;
    gemm128(A, Wt, 384, LTOT, rowBase, colBase, tid, As, Bs, acc);
    EPI_SETUP
#pragma unroll
    for (int c = 0; c < 8; c++) {
        int col = colBase + c * 16 + n16;
        float bcol = bias[col];
#pragma unroll
        for (int rt = 0; rt < 2; rt++)
#pragma unroll
        for (int reg = 0; reg < 4; reg++) {
            int r = rowBase + wv * 32 + rt * 16 + quad * 4 + reg;
            if (r < LTOT) {
                size_t rl = (size_t)(r - rowOfs);
                h1c[rl * 1536 + col] = f2b(gelu_fast(acc[rt][c][reg] + bcol));
            }
        }
    }
}

// MLP2 (K=1536, N=384) + bias + residual x2 (bf16) -> out f32 (final).
__global__ __launch_bounds__(256) void k_gemm_mlp2(
    const u16* __restrict__ A, const u16* __restrict__ Wt, const float* __restrict__ bias,
    const u16* __restrict__ x2, float* __restrict__ out, int rowOfs, int chunkRows)
{
    __shared__ __align__(16) u16 As[128][BPAD];
    __shared__ __align__(16) u16 Bs[128][BPAD];
    f32x4 acc[2][8] = {};
    int tid = threadIdx.x;
    int rowBase = blockIdx.x * 128, colBase = blockIdx.y * 128;   // local rows
    gemm128(A, Wt, 1536, chunkRows, rowBase, colBase, tid, As, Bs, acc);
    EPI_SETUP
#pragma unroll
    for (int c = 0; c < 8; c++) {
        int col = colBase + c * 16 + n16;
        float bcol = bias[col];
#pragma unroll
        for (int rt = 0; rt < 2; rt++)
#pragma unroll
        for (int reg = 0; reg < 4; reg++) {
            int rl = rowBase + wv * 32 + rt * 16 + quad * 4 + reg;
            int rg = rowOfs + rl;
            if (rl < chunkRows && rg < LTOT) {
                size_t idx = (size_t)rg * C_DIM + col;
                out[idx] = acc[rt][c][reg] + bcol + u2f(x2[idx]);
            }
        }
    }
}

// ---------------------------------------------------------------------------
// Kernel 3: MFMA flash attention, two-pass softmax, S in registers.
// Block = (head, window, half); 256 thr = 4 waves; each half does 11 q-tiles.
// ---------------------------------------------------------------------------
#define KP 40      // K / P row stride (u16)
#define VP 360     // Vt row stride (u16)

__global__ __launch_bounds__(256, 2) void k_attn(
    const u16* __restrict__ qW, const u16* __restrict__ Kb, const u16* __restrict__ Vb,
    const float* __restrict__ rpb, u16* __restrict__ oT)
{
    __shared__ __align__(16) u16 Ks[352 * KP];      // 28160 B
    __shared__ __align__(16) u16 Vt[32 * VP];       // 23040 B
    __shared__ __align__(16) u16 rp16[2208];        //  4416 B
    __shared__ __align__(16) u16 code[352];         //   704 B
    __shared__ __align__(16) u16 Pb[4 * 16 * KP];   //  5120 B

    const int h = blockIdx.x, w = blockIdx.y, half = blockIdx.z;
    const int tid = threadIdx.x;
    const int lane = tid & 63, wv = tid >> 6;
    const int m16 = lane & 15, quad = lane >> 4;
    const size_t base = ((size_t)(w * NHEAD + h)) * NTOK * HD;

    for (int t = tid; t < 1408; t += 256) {
        int r = t >> 2, c = (t & 3) << 3;
        uint4 u = make_uint4(0, 0, 0, 0);
        if (r < NTOK) u = *(const uint4*)(Kb + base + r * HD + c);
        *(uint4*)&Ks[r * KP + c] = u;
    }
    for (int t = tid; t < 1408; t += 256) {
        int dg = t / 352, n = t - dg * 352;
        uint4 u = make_uint4(0, 0, 0, 0);
        if (n < NTOK) u = *(const uint4*)(Vb + base + n * HD + dg * 8);
        int d0 = dg * 8;
        Vt[(d0 + 0) * VP + n] = (u16)(u.x & 0xffff);
        Vt[(d0 + 1) * VP + n] = (u16)(u.x >> 16);
        Vt[(d0 + 2) * VP + n] = (u16)(u.y & 0xffff);
        Vt[(d0 + 3) * VP + n] = (u16)(u.y >> 16);
        Vt[(d0 + 4) * VP + n] = (u16)(u.z & 0xffff);
        Vt[(d0 + 5) * VP + n] = (u16)(u.z >> 16);
        Vt[(d0 + 6) * VP + n] = (u16)(u.w & 0xffff);
        Vt[(d0 + 7) * VP + n] = (u16)(u.w >> 16);
    }
    for (int t = tid; t < 2208; t += 256)
        rp16[t] = (t < 2197) ? f2b(rpb[t * NHEAD + h]) : (u16)0;
    for (int t = tid; t < 352; t += 256) {
        int z = t / 49, rem = t % 49, y = rem / 7, x = rem % 7;
        code[t] = (t < NTOK) ? (u16)(z * 169 + y * 13 + x) : (u16)1098;
    }
    __syncthreads();

    const float scale = 0.17677669529663687f;  // 1/sqrt(32)
    u16* myP = Pb + wv * 16 * KP;

    for (int qt = half * 11 + wv; qt < half * 11 + 11; qt += 4) {
        int qbase = qt * 16;
        int qrow = min(qbase + m16, NTOK - 1);
        s16x8 qf = *(const s16x8*)(qW + ((size_t)(w * NTOK + qrow)) * C_DIM
                                       + h * HD + quad * 8);
        int qcv[4];
#pragma unroll
        for (int i = 0; i < 4; i++) qcv[i] = code[qbase + quad * 4 + i];

        f32x4 S0[11], S1[11];
        float mx[4] = {-1e30f, -1e30f, -1e30f, -1e30f};

#pragma unroll
        for (int ks = 0; ks < 11; ks++) {
            int kbase = ks * 32;
            int kt0 = kbase + m16, kt1 = kt0 + 16;
            s16x8 kf0 = *(const s16x8*)&Ks[kt0 * KP + quad * 8];
            s16x8 kf1 = *(const s16x8*)&Ks[kt1 * KP + quad * 8];
            f32x4 z = {0.f, 0.f, 0.f, 0.f};
            f32x4 sA = __builtin_amdgcn_mfma_f32_16x16x32_bf16(qf, kf0, z, 0, 0, 0);
            f32x4 sB = __builtin_amdgcn_mfma_f32_16x16x32_bf16(qf, kf1, z, 0, 0, 0);
            int kc0 = code[kt0], kc1 = code[kt1];
            bool k1ok = (ks < 10) || (kt1 < NTOK);
#pragma unroll
            for (int i = 0; i < 4; i++) {
                float b0 = u2f(rp16[qcv[i] - kc0 + 1098]);
                float b1 = u2f(rp16[qcv[i] - kc1 + 1098]);
                float sa = fmaf(sA[i], scale, b0);
                float sb = k1ok ? fmaf(sB[i], scale, b1) : -1e30f;
                S0[ks][i] = sa;
                S1[ks][i] = sb;
                mx[i] = fmaxf(mx[i], fmaxf(sa, sb));
            }
        }
#pragma unroll
        for (int i = 0; i < 4; i++) {
            float v = mx[i];
            v = fmaxf(v, __shfl_xor(v, 1));
            v = fmaxf(v, __shfl_xor(v, 2));
            v = fmaxf(v, __shfl_xor(v, 4));
            v = fmaxf(v, __shfl_xor(v, 8));
            mx[i] = v;
        }

        f32x4 O0 = {}, O1 = {};
        float l[4] = {};
#pragma unroll
        for (int ks = 0; ks < 11; ks++) {
            int kbase = ks * 32;
#pragma unroll
            for (int i = 0; i < 4; i++) {
                float pa = __expf(S0[ks][i] - mx[i]);
                float pb = __expf(S1[ks][i] - mx[i]);
                l[i] += pa + pb;
                int prow = quad * 4 + i;
                myP[prow * KP + m16]      = f2b(pa);
                myP[prow * KP + 16 + m16] = f2b(pb);
            }
            s16x8 pf  = *(const s16x8*)&myP[m16 * KP + quad * 8];
            s16x8 vf0 = *(const s16x8*)&Vt[m16 * VP + kbase + quad * 8];
            s16x8 vf1 = *(const s16x8*)&Vt[(16 + m16) * VP + kbase + quad * 8];
            O0 = __builtin_amdgcn_mfma_f32_16x16x32_bf16(pf, vf0, O0, 0, 0, 0);
            O1 = __builtin_amdgcn_mfma_f32_16x16x32_bf16(pf, vf1, O1, 0, 0, 0);
        }
#pragma unroll
        for (int i = 0; i < 4; i++) {
            float v = l[i];
            v += __shfl_xor(v, 1);
            v += __shfl_xor(v, 2);
            v += __shfl_xor(v, 4);
            v += __shfl_xor(v, 8);
            l[i] = v;
        }

        int wd = w >> 4, wh = (w >> 2) & 3, wwi = w & 3;
#pragma unroll
        for (int i = 0; i < 4; i++) {
            int q = qbase + quad * 4 + i;
            if (q < NTOK) {
                float rl = 1.f / l[i];
                int qz = q / 49, qrem = q % 49, qy = qrem / 7, qx = qrem % 7;
                size_t tok = ((size_t)(wd * 7 + qz) * SIDE + (wh * 7 + qy)) * SIDE
                             + (wwi * 7 + qx);
                u16* op = oT + tok * C_DIM + h * HD;
                op[m16]      = f2b(O0[i] * rl);
                op[16 + m16] = f2b(O1[i] * rl);
            }
        }
    }
}

// ---------------------------------------------------------------------------
// Workspace: 4 x BUF (67.4 MB) + 3.24 MB weights [+ h1 tail].
// res (bf16, token layout) lives in d_out scratch (dead until mlp2 writes).
// ---------------------------------------------------------------------------
extern "C" void kernel_launch(void* const* d_in, const int* in_sizes, int n_in,
                              void* d_out, int out_size, void* d_ws, size_t ws_size,
                              hipStream_t stream)
{
    const float* skip = (const float*)d_in[0];
    const float* xup  = (const float*)d_in[1];
    const float* ln1g = (const float*)d_in[5];
    const float* ln1b = (const float*)d_in[6];
    const float* kvw  = (const float*)d_in[7];
    const float* kvb  = (const float*)d_in[8];
    const float* rpb  = (const float*)d_in[9];
    const float* pw   = (const float*)d_in[10];
    const float* pb   = (const float*)d_in[11];
    const float* ln2g = (const float*)d_in[12];
    const float* ln2b = (const float*)d_in[13];
    const float* w1   = (const float*)d_in[14];
    const float* b1   = (const float*)d_in[15];
    const float* w2   = (const float*)d_in[16];
    const float* b2   = (const float*)d_in[17];
    float* out = (float*)d_out;

    char* ws = (char*)d_ws;
    const size_t BUFB = (size_t)LTOT * C_DIM * 2;   // 16,859,136 B
    const size_t WTB  = 589824 + 294912 + 1179648 + 1179648;  // 3,244,032 B
    u16* skW = (u16*)(ws);
    u16* qW  = (u16*)(ws + BUFB);
    u16* Kb  = (u16*)(ws + 2 * BUFB);
    u16* Vb  = (u16*)(ws + 3 * BUFB);
    u16* oT  = (u16*)(ws);                  // overlays skW (dead)
    u16* x2  = (u16*)(ws + BUFB);           // overlays qW (dead)
    u16* lnx = (u16*)(ws + 2 * BUFB);       // overlays Kb (dead)
    char* wt = ws + 4 * BUFB;
    u16* kvWt = (u16*)(wt);
    u16* pWt  = (u16*)(wt + 589824);
    u16* w1t  = (u16*)(wt + 589824 + 294912);
    u16* w2t  = (u16*)(wt + 589824 + 294912 + 1179648);
    u16* res  = (u16*)d_out;                // scratch in d_out (dead until mlp2)

    // h1 chunking in units of 128-row blocks (172 total).
    const size_t used = 4 * BUFB + WTB;
    const size_t blkBytes = 128 * 1536 * 2;         // 393,216 B
    size_t tailCap = (ws_size > used) ? (ws_size - used) / blkBytes : 0;
    int chunkBlocks;
    u16* h1c;
    if (tailCap >= 43) {
        chunkBlocks = tailCap < 172 ? (int)tailCap : 172;
        h1c = (u16*)(ws + used);
    } else {
        chunkBlocks = 42;                            // fits in s3 (Vb, dead)
        h1c = (u16*)(ws + 3 * BUFB);
    }

    k_wt<<<dim3(6, 12), 256, 0, stream>>>(kvw, kvWt, 384, 768);
    k_wt<<<dim3(6, 6),  256, 0, stream>>>(pw,  pWt,  384, 384);
    k_wt<<<dim3(6, 24), 256, 0, stream>>>(w1,  w1t,  384, 1536);
    k_wt<<<dim3(24, 6), 256, 0, stream>>>(w2,  w2t,  1536, 384);

    k_lnprep<<<LTOT / 4, 256, 0, stream>>>(skip, xup, ln1g, ln1b, skW, qW, res);
    k_gemm_kv<<<dim3(172, 6), 256, 0, stream>>>(skW, kvWt, kvb, Kb, Vb);
    k_attn<<<dim3(NHEAD, NWIN, 2), 256, 0, stream>>>(qW, Kb, Vb, rpb, oT);
    k_gemm_proj<<<dim3(172, 3), 256, 0, stream>>>(oT, pWt, pb, res, x2);
    k_ln2<<<LTOT / 4, 256, 0, stream>>>(x2, ln2g, ln2b, lnx);
    for (int b0 = 0; b0 < 172; b0 += chunkBlocks) {
        int nb = (172 - b0) < chunkBlocks ? (172 - b0) : chunkBlocks;
        int rowOfs = b0 * 128;
        int chunkRows = nb * 128;
        if (rowOfs + chunkRows > LTOT) chunkRows = LTOT - rowOfs;
        k_gemm_mlp1<<<dim3(nb, 12), 256, 0, stream>>>(lnx, w1t, b1, h1c, rowOfs);
        k_gemm_mlp2<<<dim3(nb, 3), 256, 0, stream>>>(h1c, w2t, b2, x2, out, rowOfs, chunkRows);
    }
}